// Round 5
// baseline (425.683 us; speedup 1.0000x reference)
//
#include <hip/hip_runtime.h>
#include <hip/hip_bf16.h>

typedef __attribute__((ext_vector_type(8))) short bf16x8;
typedef __attribute__((ext_vector_type(4))) float f32x4;
typedef __attribute__((ext_vector_type(4))) int int4v;

#define DEV static __device__ __forceinline__

DEV float b2f(unsigned short u) { union { unsigned int i; float f; } c; c.i = ((unsigned int)u) << 16; return c.f; }
DEV unsigned short f2b(float f) {
  __hip_bfloat16 h = __float2bfloat16(f);
  unsigned short u; __builtin_memcpy(&u, &h, 2); return u;
}

// async global->LDS 16B per lane; LDS dest is wave-uniform base + lane*16 (HK cast pattern)
DEV void gload16(const void* g, void* l) {
  __builtin_amdgcn_global_load_lds(
      (const __attribute__((address_space(1))) unsigned int*)(g),
      (__attribute__((address_space(3))) unsigned int*)(l), 16, 0, 0);
}

// ---------------- transpose 1024x1024 fp32 -> bf16 (transposed) ----------------
__global__ __launch_bounds__(256) void k_transpose_w(const float* __restrict__ W,
                                                     unsigned short* __restrict__ Wt) {
  __shared__ float tile[32][33];
  const int tx = threadIdx.x & 31, ty = threadIdx.x >> 5;
  const int c0 = blockIdx.x * 32, r0 = blockIdx.y * 32;
#pragma unroll
  for (int i = 0; i < 4; ++i)
    tile[ty + i * 8][tx] = W[(size_t)(r0 + ty + i * 8) * 1024 + c0 + tx];
  __syncthreads();
#pragma unroll
  for (int i = 0; i < 4; ++i)
    Wt[(size_t)(c0 + ty + i * 8) * 1024 + r0 + tx] = f2b(tile[tx][ty + i * 8]);
}

// ---------------- per-batch sum of squares ----------------
__global__ __launch_bounds__(256) void k_reduce_sq(const float* __restrict__ x,
                                                   float* __restrict__ sums) {
  const int b = blockIdx.y;
  const float4* xb = (const float4*)(x + (size_t)b * 2097152);
  float s = 0.f;
  for (int i = blockIdx.x * 256 + threadIdx.x; i < 524288; i += 256 * gridDim.x) {
    float4 v = xb[i];
    s += v.x * v.x + v.y * v.y + v.z * v.z + v.w * v.w;
  }
  __shared__ float red[256];
  red[threadIdx.x] = s;
  __syncthreads();
  for (int st = 128; st > 0; st >>= 1) {
    if (threadIdx.x < st) red[threadIdx.x] += red[threadIdx.x + st];
    __syncthreads();
  }
  if (threadIdx.x == 0) atomicAdd(&sums[b], red[0]);
}

// ---------------- rmsnorm ----------------
__global__ __launch_bounds__(256) void k_rmsnorm(const float* __restrict__ x,
                                                 const float* __restrict__ scale,
                                                 const float* __restrict__ sums,
                                                 unsigned short* __restrict__ out) {
  const int idx = blockIdx.x * 256 + threadIdx.x;
  const int e = idx * 4;
  const int m = e >> 10, d = e & 1023;
  const int b = m >> 11, s = m & 2047;
  const float inv = rsqrtf(sums[b] * (1.0f / 2097152.0f));
  float4 xv = *(const float4*)(x + (size_t)e);
  float4 sv = *(const float4*)(scale + (size_t)s * 1024 + d);
  ushort4 o;
  o.x = f2b(xv.x * sv.x * inv); o.y = f2b(xv.y * sv.y * inv);
  o.z = f2b(xv.z * sv.z * inv); o.w = f2b(xv.w * sv.w * inv);
  *(ushort4*)(out + e) = o;
}

// ---------------- GEMM: C[4096,N] = A[4096,1024] @ Bt[N,1024]^T ----------------
// BM = MREP*32. global_load_lds staging, linear LDS (T2 null at 2-phase; m151).
// EPI 0: bf16 store. EPI 1: fp32 (aux[row,col]+acc). EPI 2: bf16 (acc+aux[col]).
template <int EPI, int MREP>
__global__ __launch_bounds__(256) void k_gemm(const unsigned short* __restrict__ A,
                                              const unsigned short* __restrict__ Bt,
                                              void* __restrict__ Cout,
                                              const float* __restrict__ aux,
                                              const int N) {
  constexpr int BM = MREP * 32;
  __shared__ short As[BM * 64];
  __shared__ short Bs[128 * 64];
  const int tid = threadIdx.x;
  const int w = tid >> 6, l = tid & 63;
  const int brow = blockIdx.y * BM, bcol = blockIdx.x * 128;
  const int wr = (w >> 1) * (MREP * 16), wc = (w & 1) * 64;
  const int lr = l >> 3, lg = l & 7;
  f32x4 acc[MREP][4] = {};
  const short* Ag = (const short*)A;
  const short* Bg = (const short*)Bt;
  for (int k0 = 0; k0 < 1024; k0 += 64) {
    __syncthreads();  // previous compute done reading LDS
#pragma unroll
    for (int p = 0; p < MREP; ++p) {
      const int row = p * 32 + w * 8 + lr;
      gload16(Ag + (size_t)(brow + row) * 1024 + k0 + lg * 8,
              (char*)As + (size_t)(p * 32 + w * 8) * 128);
    }
#pragma unroll
    for (int p = 0; p < 4; ++p) {
      const int row = p * 32 + w * 8 + lr;
      gload16(Bg + (size_t)(bcol + row) * 1024 + k0 + lg * 8,
              (char*)Bs + (size_t)(p * 32 + w * 8) * 128);
    }
    __syncthreads();  // drains vmcnt -> LDS data visible
#pragma unroll
    for (int kk = 0; kk < 2; ++kk) {
      const int g0 = kk * 4 + (l >> 4);
      bf16x8 af[MREP], bfr[4];
#pragma unroll
      for (int m = 0; m < MREP; ++m)
        af[m] = *(const bf16x8*)(As + (wr + m * 16 + (l & 15)) * 64 + g0 * 8);
#pragma unroll
      for (int n = 0; n < 4; ++n)
        bfr[n] = *(const bf16x8*)(Bs + (wc + n * 16 + (l & 15)) * 64 + g0 * 8);
#pragma unroll
      for (int m = 0; m < MREP; ++m)
#pragma unroll
        for (int n = 0; n < 4; ++n)
          acc[m][n] = __builtin_amdgcn_mfma_f32_16x16x32_bf16(af[m], bfr[n], acc[m][n], 0, 0, 0);
    }
  }
  const int rr = (l >> 4) * 4, cc = l & 15;
#pragma unroll
  for (int m = 0; m < MREP; ++m)
#pragma unroll
    for (int n = 0; n < 4; ++n) {
      const int col = bcol + wc + n * 16 + cc;
#pragma unroll
      for (int j = 0; j < 4; ++j) {
        const int row = brow + wr + m * 16 + rr + j;
        float v = acc[m][n][j];
        if (EPI == 0) {
          ((unsigned short*)Cout)[(size_t)row * N + col] = f2b(v);
        } else if (EPI == 1) {
          ((float*)Cout)[(size_t)row * N + col] = aux[(size_t)row * N + col] + v;
        } else {
          ((unsigned short*)Cout)[(size_t)row * N + col] = f2b(v + aux[col]);
        }
      }
    }
}

// ---------------- RoPE in place over qkv [4096][3072] bf16 ----------------
__global__ __launch_bounds__(256) void k_rope(unsigned int* __restrict__ qkv32) {
  const int p = blockIdx.x * 256 + threadIdx.x;
  const int m = p / 1536;
  const int pc = p - m * 1536;
  const int s = m & 2047;
  const int i = pc & 511;
  const float theta = expf(-((float)i - 1.0f) * 0.017988946039016f);
  const float ang = (float)s * theta;
  float sn, cs;
  sincosf(ang, &sn, &cs);
  unsigned int v = qkv32[p];
  float xe = b2f((unsigned short)(v & 0xffffu));
  float xo = b2f((unsigned short)(v >> 16));
  float oe = xe * cs + xo * sn;
  float oo = -xe * sn + xo * cs;
  qkv32[p] = (unsigned int)f2b(oe) | ((unsigned int)f2b(oo) << 16);
}

// ---------------- V transpose ----------------
__global__ __launch_bounds__(256) void k_transpose_v(const unsigned short* __restrict__ qkv,
                                                     unsigned short* __restrict__ vt) {
  __shared__ unsigned short tile[32][33];
  const int tx = threadIdx.x & 31, ty = threadIdx.x >> 5;
  const int bh = blockIdx.z;
  const int b = bh >> 4, h = bh & 15;
  const int d0 = blockIdx.x * 32, s0 = blockIdx.y * 32;
#pragma unroll
  for (int i = 0; i < 4; ++i)
    tile[ty + i * 8][tx] = qkv[(size_t)(b * 2048 + s0 + ty + i * 8) * 3072 + 2048 + h * 64 + d0 + tx];
  __syncthreads();
#pragma unroll
  for (int i = 0; i < 4; ++i)
    vt[((size_t)bh * 64 + d0 + ty + i * 8) * 2048 + s0 + tx] = tile[tx][ty + i * 8];
}

// ---------------- flash attention v2: ALiBi + causal, intra-block KV-split ----------------
// grid (qt=32, H=16, B=2), 512 threads = 8 waves.
// wave w: qsub=w&3 (16 q rows), kvpar=w>>2 (even/odd KV tiles). Merge partials at end.
__global__ __launch_bounds__(512) void k_attn(const unsigned short* __restrict__ qkv,
                                              const unsigned short* __restrict__ vt,
                                              unsigned short* __restrict__ o) {
  __shared__ char smem[53248];
  short* Ks = (short*)smem;            // [2][64][64] 16KB
  short* Vs = Ks + 8192;               // [2][64][64] 16KB
  short* Ps = Vs + 8192;               // [8][16][80] 20KB
  const int qt = blockIdx.x, h = blockIdx.y, b = blockIdx.z;
  const int tid = threadIdx.x, w = tid >> 6, l = tid & 63;
  const int qsub = w & 3, kvpar = w >> 2;
  const int qw = qt * 64 + qsub * 16;
  const short* qg = (const short*)qkv;
  bf16x8 aq[2];
  {
    const int row = qw + (l & 15);
    const short* base = qg + (size_t)(b * 2048 + row) * 3072 + h * 64 + (l >> 4) * 8;
    aq[0] = *(const bf16x8*)(base);
    aq[1] = *(const bf16x8*)(base + 32);
  }
  const float slope = exp2f(-0.5f * (float)(h + 1));
  f32x4 oacc[4] = {};
  float mrun[4] = {-1e30f, -1e30f, -1e30f, -1e30f};
  float lrun[4] = {0.f, 0.f, 0.f, 0.f};
  short* Pw = Ps + w * 1280;
  const int tid2 = tid & 255, bi = tid >> 8;       // staging: 256 threads per buffer
  const int st_r = tid2 >> 3, st_g = tid2 & 7;
  const int nt = qt + 1, itn = (nt + 1) >> 1;
  short* Ksc = Ks + kvpar * 4096;
  short* Vsc = Vs + kvpar * 4096;
  for (int it = 0; it < itn; ++it) {
    __syncthreads();
    const int ts = 2 * it + bi;
    if (ts < nt) {
      const int kv0s = ts * 64;
      short* Ksb = Ks + bi * 4096;
      short* Vsb = Vs + bi * 4096;
#pragma unroll
      for (int p = 0; p < 2; ++p) {
        const int r = p * 32 + st_r;
        const int sidx = r * 64 + ((st_g ^ (r & 7)) * 8);
        *(int4v*)(Ksb + sidx) =
            *(const int4v*)(qg + (size_t)(b * 2048 + kv0s + r) * 3072 + 1024 + h * 64 + st_g * 8);
        *(int4v*)(Vsb + sidx) =
            *(const int4v*)((const short*)vt + ((size_t)(b * 16 + h) * 64 + r) * 2048 + kv0s + st_g * 8);
      }
    }
    __syncthreads();
    const int tc = 2 * it + kvpar;
    if (tc >= nt) continue;
    const int kv0 = tc * 64;
    f32x4 sacc[4] = {};
#pragma unroll
    for (int kk = 0; kk < 2; ++kk) {
      const int g0 = kk * 4 + (l >> 4);
#pragma unroll
      for (int n = 0; n < 4; ++n) {
        const int col = n * 16 + (l & 15);
        bf16x8 bk = *(const bf16x8*)(Ksc + col * 64 + ((g0 ^ (col & 7)) * 8));
        sacc[n] = __builtin_amdgcn_mfma_f32_16x16x32_bf16(aq[kk], bk, sacc[n], 0, 0, 0);
      }
    }
    float pv[4][4];
    float rm[4] = {-3e30f, -3e30f, -3e30f, -3e30f};
#pragma unroll
    for (int n = 0; n < 4; ++n) {
      const int kvg = kv0 + n * 16 + (l & 15);
#pragma unroll
      for (int j = 0; j < 4; ++j) {
        const int qrow = qw + (l >> 4) * 4 + j;
        float v;
        if (kvg <= qrow) v = sacc[n][j] * 0.125f + slope * (float)(kvg - qrow);
        else v = -1e30f;
        pv[n][j] = v;
        rm[j] = fmaxf(rm[j], v);
      }
    }
#pragma unroll
    for (int j = 0; j < 4; ++j) {
      rm[j] = fmaxf(rm[j], __shfl_xor(rm[j], 1));
      rm[j] = fmaxf(rm[j], __shfl_xor(rm[j], 2));
      rm[j] = fmaxf(rm[j], __shfl_xor(rm[j], 4));
      rm[j] = fmaxf(rm[j], __shfl_xor(rm[j], 8));
    }
    float corr[4], rs[4];
#pragma unroll
    for (int j = 0; j < 4; ++j) {
      const float mn = fmaxf(mrun[j], rm[j]);
      corr[j] = __expf(mrun[j] - mn);
      mrun[j] = mn;
      rs[j] = 0.f;
    }
#pragma unroll
    for (int n = 0; n < 4; ++n)
#pragma unroll
      for (int j = 0; j < 4; ++j) {
        const float e = __expf(pv[n][j] - mrun[j]);
        pv[n][j] = e;
        rs[j] += e;
      }
#pragma unroll
    for (int j = 0; j < 4; ++j) {
      rs[j] += __shfl_xor(rs[j], 1);
      rs[j] += __shfl_xor(rs[j], 2);
      rs[j] += __shfl_xor(rs[j], 4);
      rs[j] += __shfl_xor(rs[j], 8);
      lrun[j] = lrun[j] * corr[j] + rs[j];
    }
#pragma unroll
    for (int n = 0; n < 4; ++n)
#pragma unroll
      for (int j = 0; j < 4; ++j) oacc[n][j] *= corr[j];
#pragma unroll
    for (int n = 0; n < 4; ++n)
#pragma unroll
      for (int j = 0; j < 4; ++j)
        Pw[((l >> 4) * 4 + j) * 80 + n * 16 + (l & 15)] = (short)f2b(pv[n][j]);
#pragma unroll
    for (int kk2 = 0; kk2 < 2; ++kk2) {
      bf16x8 pf = *(const bf16x8*)(Pw + (l & 15) * 80 + kk2 * 32 + (l >> 4) * 8);
#pragma unroll
      for (int n = 0; n < 4; ++n) {
        const int dr = n * 16 + (l & 15);
        bf16x8 vf = *(const bf16x8*)(Vsc + dr * 64 + (((kk2 * 4 + (l >> 4)) ^ (dr & 7)) * 8));
        oacc[n] = __builtin_amdgcn_mfma_f32_16x16x32_bf16(pf, vf, oacc[n], 0, 0, 0);
      }
    }
  }
  // ---- merge the two KV-parity partials (group1 -> LDS, group0 combines+stores) ----
  __syncthreads();
  float* Om = (float*)smem;              // [4][16][64] 16KB (aliases Ks/Vs, dead now)
  float* Mm = (float*)(smem + 16384);    // [4][16]
  float* Lm = (float*)(smem + 16640);    // [4][16]
  const int rr = (l >> 4) * 4, cc = l & 15;
  if (kvpar == 1) {
#pragma unroll
    for (int n = 0; n < 4; ++n)
#pragma unroll
      for (int j = 0; j < 4; ++j)
        Om[qsub * 1024 + (rr + j) * 64 + n * 16 + cc] = oacc[n][j];
#pragma unroll
    for (int j = 0; j < 4; ++j) {
      Mm[qsub * 16 + rr + j] = mrun[j];
      Lm[qsub * 16 + rr + j] = lrun[j];
    }
  }
  __syncthreads();
  if (kvpar == 0) {
    float c0[4], c1[4], linv[4];
#pragma unroll
    for (int j = 0; j < 4; ++j) {
      const float m1 = Mm[qsub * 16 + rr + j];
      const float l1 = Lm[qsub * 16 + rr + j];
      const float mn = fmaxf(mrun[j], m1);
      c0[j] = __expf(mrun[j] - mn);
      c1[j] = __expf(m1 - mn);
      linv[j] = 1.0f / (lrun[j] * c0[j] + l1 * c1[j]);
    }
#pragma unroll
    for (int n = 0; n < 4; ++n)
#pragma unroll
      for (int j = 0; j < 4; ++j) {
        const int row = qw + rr + j;
        const int col = h * 64 + n * 16 + cc;
        const float ov = oacc[n][j] * c0[j] + Om[qsub * 1024 + (rr + j) * 64 + n * 16 + cc] * c1[j];
        o[(size_t)(b * 2048 + row) * 1024 + col] = f2b(ov * linv[j]);
      }
  }
}

// ---------------- final: out = x1 + swish(g)*lin ----------------
__global__ __launch_bounds__(256) void k_final(const float* __restrict__ x1,
                                               const unsigned short* __restrict__ gl,
                                               const float* __restrict__ beta,
                                               float* __restrict__ out) {
  const int idx = blockIdx.x * 256 + threadIdx.x;
  const int e = idx * 4;
  const int m = e >> 10, d = e & 1023;
  const float bt = beta[0];
  ushort4 gu = *(const ushort4*)(gl + (size_t)m * 2048 + d);
  ushort4 lu = *(const ushort4*)(gl + (size_t)m * 2048 + 1024 + d);
  float4 xv = *(const float4*)(x1 + e);
  float g0 = b2f(gu.x), g1 = b2f(gu.y), g2 = b2f(gu.z), g3 = b2f(gu.w);
  float l0 = b2f(lu.x), l1 = b2f(lu.y), l2 = b2f(lu.z), l3 = b2f(lu.w);
  float4 r;
  r.x = xv.x + g0 / (1.f + __expf(-bt * g0)) * l0;
  r.y = xv.y + g1 / (1.f + __expf(-bt * g1)) * l1;
  r.z = xv.z + g2 / (1.f + __expf(-bt * g2)) * l2;
  r.w = xv.w + g3 / (1.f + __expf(-bt * g3)) * l3;
  *(float4*)(out + e) = r;
}

extern "C" void kernel_launch(void* const* d_in, const int* in_sizes, int n_in,
                              void* d_out, int out_size, void* d_ws, size_t ws_size,
                              hipStream_t stream) {
  (void)in_sizes; (void)n_in; (void)out_size; (void)ws_size;
  const float* x      = (const float*)d_in[0];
  const float* Wq     = (const float*)d_in[1];
  const float* Wk     = (const float*)d_in[2];
  const float* Wv     = (const float*)d_in[3];
  const float* Wo     = (const float*)d_in[4];
  const float* scale1 = (const float*)d_in[5];
  const float* scale2 = (const float*)d_in[6];
  const float* W1     = (const float*)d_in[7];
  const float* b1     = (const float*)d_in[8];
  const float* Wg     = (const float*)d_in[9];
  const float* bg     = (const float*)d_in[10];
  const float* Wl     = (const float*)d_in[11];
  const float* bl     = (const float*)d_in[12];
  const float* beta   = (const float*)d_in[13];
  float* out = (float*)d_out;

  char* ws = (char*)d_ws;
  float* sums         = (float*)ws;                       // 256 B (4 used)
  float* bgl          = (float*)(ws + 256);               // 2048 floats
  unsigned short* WT  = (unsigned short*)(ws + 16384);                 // 3M bf16 (6 MB)
  unsigned short* h   = (unsigned short*)(ws + 16384 + 6291456);       // 4M bf16 (8 MB)
  unsigned short* qkv = (unsigned short*)((char*)h + 8388608);         // 12M bf16 (24 MB)
  unsigned short* vt  = (unsigned short*)((char*)qkv + 25165824);      // 4M bf16 (8 MB)
  unsigned short* ob  = (unsigned short*)((char*)vt + 8388608);        // 4M bf16 (8 MB)
  float* x1           = (float*)((char*)ob + 8388608);                 // 4M fp32 (16 MB)
  unsigned short* t1  = qkv;                 // reuse (qkv dead after attention)
  unsigned short* gl  = qkv + 4194304;       // reuse, 8M bf16

  hipMemsetAsync(sums, 0, 256, stream);

  // --- attention sublayer ---
  k_transpose_w<<<dim3(32, 32), 256, 0, stream>>>(Wq, WT);
  k_transpose_w<<<dim3(32, 32), 256, 0, stream>>>(Wk, WT + 1048576);
  k_transpose_w<<<dim3(32, 32), 256, 0, stream>>>(Wv, WT + 2097152);
  k_reduce_sq<<<dim3(256, 2), 256, 0, stream>>>(x, sums);
  k_rmsnorm<<<4096, 256, 0, stream>>>(x, scale1, sums, h);
  k_gemm<0, 4><<<dim3(24, 32), 256, 0, stream>>>(h, WT, (void*)qkv, nullptr, 3072);
  k_rope<<<24576, 256, 0, stream>>>((unsigned int*)qkv);
  k_transpose_v<<<dim3(2, 64, 32), 256, 0, stream>>>(qkv, vt);
  k_attn<<<dim3(32, 16, 2), 512, 0, stream>>>(qkv, vt, ob);
  k_transpose_w<<<dim3(32, 32), 256, 0, stream>>>(Wo, WT);
  k_gemm<1, 2><<<dim3(8, 64), 256, 0, stream>>>(ob, WT, (void*)x1, x, 1024);

  // --- FFN sublayer ---
  k_reduce_sq<<<dim3(256, 2), 256, 0, stream>>>(x1, sums + 2);
  k_rmsnorm<<<4096, 256, 0, stream>>>(x1, scale2, sums + 2, h);
  k_transpose_w<<<dim3(32, 32), 256, 0, stream>>>(W1, WT);
  k_gemm<2, 2><<<dim3(8, 64), 256, 0, stream>>>(h, WT, (void*)t1, b1, 1024);
  k_transpose_w<<<dim3(32, 32), 256, 0, stream>>>(Wg, WT);
  k_transpose_w<<<dim3(32, 32), 256, 0, stream>>>(Wl, WT + 1048576);
  hipMemcpyAsync(bgl, bg, 4096, hipMemcpyDeviceToDevice, stream);
  hipMemcpyAsync(bgl + 1024, bl, 4096, hipMemcpyDeviceToDevice, stream);
  k_gemm<2, 4><<<dim3(16, 32), 256, 0, stream>>>(t1, WT, (void*)gl, bgl, 2048);
  k_final<<<4096, 256, 0, stream>>>(x1, gl, beta, out);
}

// Round 7
// 395.241 us; speedup vs baseline: 1.0770x; 1.0770x over previous
//
#include <hip/hip_runtime.h>
#include <hip/hip_bf16.h>

typedef __attribute__((ext_vector_type(8))) short bf16x8;
typedef __attribute__((ext_vector_type(4))) float f32x4;
typedef __attribute__((ext_vector_type(4))) int int4v;

#define DEV static __device__ __forceinline__

DEV float b2f(unsigned short u) { union { unsigned int i; float f; } c; c.i = ((unsigned int)u) << 16; return c.f; }
DEV unsigned short f2b(float f) {
  __hip_bfloat16 h = __float2bfloat16(f);
  unsigned short u; __builtin_memcpy(&u, &h, 2); return u;
}

// async global->LDS 16B per lane; LDS dest wave-uniform base + lane*16
DEV void gload16(const void* g, void* l) {
  __builtin_amdgcn_global_load_lds(
      (const __attribute__((address_space(1))) unsigned int*)(g),
      (__attribute__((address_space(3))) unsigned int*)(l), 16, 0, 0);
}

// ---------------- transpose 1024x1024 fp32 -> bf16 (transposed) ----------------
__global__ __launch_bounds__(256) void k_transpose_w(const float* __restrict__ W,
                                                     unsigned short* __restrict__ Wt) {
  __shared__ float tile[32][33];
  const int tx = threadIdx.x & 31, ty = threadIdx.x >> 5;
  const int c0 = blockIdx.x * 32, r0 = blockIdx.y * 32;
#pragma unroll
  for (int i = 0; i < 4; ++i)
    tile[ty + i * 8][tx] = W[(size_t)(r0 + ty + i * 8) * 1024 + c0 + tx];
  __syncthreads();
#pragma unroll
  for (int i = 0; i < 4; ++i)
    Wt[(size_t)(c0 + ty + i * 8) * 1024 + r0 + tx] = f2b(tile[tx][ty + i * 8]);
}

// ---------------- per-batch sum of squares ----------------
__global__ __launch_bounds__(256) void k_reduce_sq(const float* __restrict__ x,
                                                   float* __restrict__ sums) {
  const int b = blockIdx.y;
  const float4* xb = (const float4*)(x + (size_t)b * 2097152);
  float s = 0.f;
  for (int i = blockIdx.x * 256 + threadIdx.x; i < 524288; i += 256 * gridDim.x) {
    float4 v = xb[i];
    s += v.x * v.x + v.y * v.y + v.z * v.z + v.w * v.w;
  }
  __shared__ float red[256];
  red[threadIdx.x] = s;
  __syncthreads();
  for (int st = 128; st > 0; st >>= 1) {
    if (threadIdx.x < st) red[threadIdx.x] += red[threadIdx.x + st];
    __syncthreads();
  }
  if (threadIdx.x == 0) atomicAdd(&sums[b], red[0]);
}

// ---------------- rmsnorm ----------------
__global__ __launch_bounds__(256) void k_rmsnorm(const float* __restrict__ x,
                                                 const float* __restrict__ scale,
                                                 const float* __restrict__ sums,
                                                 unsigned short* __restrict__ out) {
  const int idx = blockIdx.x * 256 + threadIdx.x;
  const int e = idx * 4;
  const int m = e >> 10, d = e & 1023;
  const int b = m >> 11, s = m & 2047;
  const float inv = rsqrtf(sums[b] * (1.0f / 2097152.0f));
  float4 xv = *(const float4*)(x + (size_t)e);
  float4 sv = *(const float4*)(scale + (size_t)s * 1024 + d);
  ushort4 o;
  o.x = f2b(xv.x * sv.x * inv); o.y = f2b(xv.y * sv.y * inv);
  o.z = f2b(xv.z * sv.z * inv); o.w = f2b(xv.w * sv.w * inv);
  *(ushort4*)(out + e) = o;
}

// ---------------- GEMM: C[4096,N] = A[4096,1024] @ Bt[N,1024]^T ----------------
// BM=128, BN=NREP*32. gload_lds staging, linear LDS (m97 structure).
// EPI 0: bf16. EPI 1: fp32 (aux[row,col]+acc), fused batch sumsq -> ss. EPI 2: bf16 (acc+aux[col]).
template <int EPI, int NREP>
__global__ __launch_bounds__(256) void k_gemm(const unsigned short* __restrict__ A,
                                              const unsigned short* __restrict__ Bt,
                                              void* __restrict__ Cout,
                                              const float* __restrict__ aux,
                                              const int N,
                                              float* __restrict__ ss) {
  constexpr int BN = NREP * 32;
  __shared__ short As[128 * 64];
  __shared__ short Bs[BN * 64];
  const int tid = threadIdx.x;
  const int w = tid >> 6, l = tid & 63;
  const int brow = blockIdx.y * 128, bcol = blockIdx.x * BN;
  const int wr = (w >> 1) * 64, wc = (w & 1) * (NREP * 16);
  const int lr = l >> 3, lg = l & 7;
  f32x4 acc[4][NREP] = {};
  const short* Ag = (const short*)A;
  const short* Bg = (const short*)Bt;
  for (int k0 = 0; k0 < 1024; k0 += 64) {
    __syncthreads();
#pragma unroll
    for (int p = 0; p < 4; ++p) {
      const int row = p * 32 + w * 8 + lr;
      gload16(Ag + (size_t)(brow + row) * 1024 + k0 + lg * 8,
              (char*)As + (size_t)(p * 32 + w * 8) * 128);
    }
#pragma unroll
    for (int p = 0; p < NREP; ++p) {
      const int row = p * 32 + w * 8 + lr;
      gload16(Bg + (size_t)(bcol + row) * 1024 + k0 + lg * 8,
              (char*)Bs + (size_t)(p * 32 + w * 8) * 128);
    }
    __syncthreads();
#pragma unroll
    for (int kk = 0; kk < 2; ++kk) {
      const int g0 = kk * 4 + (l >> 4);
      bf16x8 af[4], bfr[NREP];
#pragma unroll
      for (int m = 0; m < 4; ++m)
        af[m] = *(const bf16x8*)(As + (wr + m * 16 + (l & 15)) * 64 + g0 * 8);
#pragma unroll
      for (int n = 0; n < NREP; ++n)
        bfr[n] = *(const bf16x8*)(Bs + (wc + n * 16 + (l & 15)) * 64 + g0 * 8);
#pragma unroll
      for (int m = 0; m < 4; ++m)
#pragma unroll
        for (int n = 0; n < NREP; ++n)
          acc[m][n] = __builtin_amdgcn_mfma_f32_16x16x32_bf16(af[m], bfr[n], acc[m][n], 0, 0, 0);
    }
  }
  const int rr = (l >> 4) * 4, cc = l & 15;
  float sq = 0.f;
#pragma unroll
  for (int m = 0; m < 4; ++m)
#pragma unroll
    for (int n = 0; n < NREP; ++n) {
      const int col = bcol + wc + n * 16 + cc;
#pragma unroll
      for (int j = 0; j < 4; ++j) {
        const int row = brow + wr + m * 16 + rr + j;
        float v = acc[m][n][j];
        if (EPI == 0) {
          ((unsigned short*)Cout)[(size_t)row * N + col] = f2b(v);
        } else if (EPI == 1) {
          const float v2 = aux[(size_t)row * N + col] + v;
          ((float*)Cout)[(size_t)row * N + col] = v2;
          sq += v2 * v2;
        } else {
          ((unsigned short*)Cout)[(size_t)row * N + col] = f2b(v + aux[col]);
        }
      }
    }
  if (EPI == 1) {
#pragma unroll
    for (int off = 1; off < 64; off <<= 1) sq += __shfl_xor(sq, off);
    if (l == 0) atomicAdd(&ss[brow >> 11], sq);
  }
}

// ---------------- RoPE in place over qkv [4096][3072] bf16 ----------------
__global__ __launch_bounds__(256) void k_rope(unsigned int* __restrict__ qkv32) {
  const int p = blockIdx.x * 256 + threadIdx.x;
  const int m = p / 1536;
  const int pc = p - m * 1536;
  const int s = m & 2047;
  const int i = pc & 511;
  const float theta = expf(-((float)i - 1.0f) * 0.017988946039016f);
  const float ang = (float)s * theta;
  float sn, cs;
  sincosf(ang, &sn, &cs);
  unsigned int v = qkv32[p];
  float xe = b2f((unsigned short)(v & 0xffffu));
  float xo = b2f((unsigned short)(v >> 16));
  float oe = xe * cs + xo * sn;
  float oo = -xe * sn + xo * cs;
  qkv32[p] = (unsigned int)f2b(oe) | ((unsigned int)f2b(oo) << 16);
}

// ---------------- V transpose ----------------
__global__ __launch_bounds__(256) void k_transpose_v(const unsigned short* __restrict__ qkv,
                                                     unsigned short* __restrict__ vt) {
  __shared__ unsigned short tile[32][33];
  const int tx = threadIdx.x & 31, ty = threadIdx.x >> 5;
  const int bh = blockIdx.z;
  const int b = bh >> 4, h = bh & 15;
  const int d0 = blockIdx.x * 32, s0 = blockIdx.y * 32;
#pragma unroll
  for (int i = 0; i < 4; ++i)
    tile[ty + i * 8][tx] = qkv[(size_t)(b * 2048 + s0 + ty + i * 8) * 3072 + 2048 + h * 64 + d0 + tx];
  __syncthreads();
#pragma unroll
  for (int i = 0; i < 4; ++i)
    vt[((size_t)bh * 64 + d0 + ty + i * 8) * 2048 + s0 + tx] = tile[tx][ty + i * 8];
}

// ---------------- flash attention v3: balanced pair of q-tiles, pipelined KV ----------------
// grid (16, 16, 2), 256 threads = 4 waves. Block handles q-tiles qtA=bx, qtB=31-bx:
// every block does exactly 33 KV-tile iterations. Double-buffered K/V, prefetch
// next tile to regs before compute (T14), one barrier per iteration, setprio on MFMA.
__global__ __launch_bounds__(256) void k_attn(const unsigned short* __restrict__ qkv,
                                              const unsigned short* __restrict__ vt,
                                              unsigned short* __restrict__ o) {
  __shared__ short Ks[2][4096];
  __shared__ short Vs[2][4096];
  __shared__ short Ps[4][1280];
  const int h = blockIdx.y, b = blockIdx.z;
  const int qtA = blockIdx.x, qtB = 31 - qtA;
  const int tid = threadIdx.x, w = tid >> 6, l = tid & 63;
  const short* qg = (const short*)qkv;
  bf16x8 aqA0, aqA1, aqB0, aqB1;
  {
    const int rowA = qtA * 64 + w * 16 + (l & 15);
    const short* baseA = qg + (size_t)(b * 2048 + rowA) * 3072 + h * 64 + (l >> 4) * 8;
    aqA0 = *(const bf16x8*)(baseA);
    aqA1 = *(const bf16x8*)(baseA + 32);
    const int rowB = qtB * 64 + w * 16 + (l & 15);
    const short* baseB = qg + (size_t)(b * 2048 + rowB) * 3072 + h * 64 + (l >> 4) * 8;
    aqB0 = *(const bf16x8*)(baseB);
    aqB1 = *(const bf16x8*)(baseB + 32);
  }
  const float slope = exp2f(-0.5f * (float)(h + 1));
  f32x4 oacc[4] = {};
  float mrun[4] = {-1e30f, -1e30f, -1e30f, -1e30f};
  float lrun[4] = {0.f, 0.f, 0.f, 0.f};
  short* Pw = &Ps[w][0];
  // staging: 2 16B-chunks per thread per tile (64 rows x 8 chunks)
  const int c0 = tid, c1 = tid + 256;
  const int r0 = c0 >> 3, g0c = c0 & 7;
  const int r1 = c1 >> 3, g1c = c1 & 7;
  const int s0 = r0 * 64 + ((g0c ^ (r0 & 7)) * 8);
  const int s1 = r1 * 64 + ((g1c ^ (r1 & 7)) * 8);
  const short* kbase = qg + (size_t)(b * 2048) * 3072 + 1024 + h * 64;
  const short* vbase = (const short*)vt + (size_t)(b * 16 + h) * 64 * 2048;
  const int nA = qtA + 1;
  const int nt = 33;  // nA + qtB + 1
  // prologue: stage tile 0 into buf 0
  *(int4v*)(&Ks[0][s0]) = *(const int4v*)(kbase + (size_t)r0 * 3072 + g0c * 8);
  *(int4v*)(&Ks[0][s1]) = *(const int4v*)(kbase + (size_t)r1 * 3072 + g1c * 8);
  *(int4v*)(&Vs[0][s0]) = *(const int4v*)(vbase + (size_t)r0 * 2048 + g0c * 8);
  *(int4v*)(&Vs[0][s1]) = *(const int4v*)(vbase + (size_t)r1 * 2048 + g1c * 8);
  __syncthreads();

  auto writeout = [&](int q0w) {
    const int rr = (l >> 4) * 4, cc = l & 15;
#pragma unroll
    for (int n = 0; n < 4; ++n)
#pragma unroll
      for (int j = 0; j < 4; ++j) {
        const int row = q0w + w * 16 + rr + j;
        const int col = h * 64 + n * 16 + cc;
        o[(size_t)(b * 2048 + row) * 1024 + col] = f2b(oacc[n][j] / lrun[j]);
      }
  };

  int cur = 0;
  for (int i = 0; i < nt; ++i) {
    // ---- prefetch next tile into regs (issued before compute; latency hidden) ----
    int4v kr0, kr1, vr0, vr1;
    const int inx = i + 1;
    const bool havenext = (inx < nt);
    if (havenext) {
      const int kvn = (inx < nA) ? inx : (inx - nA);
      const size_t k0n = (size_t)kvn * 64;
      kr0 = *(const int4v*)(kbase + (k0n + r0) * 3072 + g0c * 8);
      kr1 = *(const int4v*)(kbase + (k0n + r1) * 3072 + g1c * 8);
      vr0 = *(const int4v*)(vbase + (size_t)r0 * 2048 + k0n + g0c * 8);
      vr1 = *(const int4v*)(vbase + (size_t)r1 * 2048 + k0n + g1c * 8);
    }
    // ---- compute tile i from buf[cur] ----
    const bool phaseB = (i >= nA);
    const int kvt = phaseB ? (i - nA) : i;
    const int kv0 = kvt * 64;
    const int q0 = (phaseB ? qtB : qtA) * 64;
    const int qw = q0 + w * 16;
    bf16x8 aq0, aq1;
    if (phaseB) { aq0 = aqB0; aq1 = aqB1; } else { aq0 = aqA0; aq1 = aqA1; }
    const short* Ksc = &Ks[cur][0];
    const short* Vsc = &Vs[cur][0];
    f32x4 sacc[4] = {};
    __builtin_amdgcn_s_setprio(1);
#pragma unroll
    for (int kk = 0; kk < 2; ++kk) {
      const int g0r = kk * 4 + (l >> 4);
      const bf16x8 aqk = kk ? aq1 : aq0;
#pragma unroll
      for (int n = 0; n < 4; ++n) {
        const int col = n * 16 + (l & 15);
        bf16x8 bk = *(const bf16x8*)(Ksc + col * 64 + ((g0r ^ (col & 7)) * 8));
        sacc[n] = __builtin_amdgcn_mfma_f32_16x16x32_bf16(aqk, bk, sacc[n], 0, 0, 0);
      }
    }
    __builtin_amdgcn_s_setprio(0);
    float pv[4][4];
    float rm[4] = {-3e30f, -3e30f, -3e30f, -3e30f};
#pragma unroll
    for (int n = 0; n < 4; ++n) {
      const int kvg = kv0 + n * 16 + (l & 15);
#pragma unroll
      for (int j = 0; j < 4; ++j) {
        const int qrow = qw + (l >> 4) * 4 + j;
        float v;
        if (kvg <= qrow) v = sacc[n][j] * 0.125f + slope * (float)(kvg - qrow);
        else v = -1e30f;
        pv[n][j] = v;
        rm[j] = fmaxf(rm[j], v);
      }
    }
#pragma unroll
    for (int j = 0; j < 4; ++j) {
      rm[j] = fmaxf(rm[j], __shfl_xor(rm[j], 1));
      rm[j] = fmaxf(rm[j], __shfl_xor(rm[j], 2));
      rm[j] = fmaxf(rm[j], __shfl_xor(rm[j], 4));
      rm[j] = fmaxf(rm[j], __shfl_xor(rm[j], 8));
    }
    float corr[4], rs[4];
#pragma unroll
    for (int j = 0; j < 4; ++j) {
      const float mn = fmaxf(mrun[j], rm[j]);
      corr[j] = __expf(mrun[j] - mn);
      mrun[j] = mn;
      rs[j] = 0.f;
    }
#pragma unroll
    for (int n = 0; n < 4; ++n)
#pragma unroll
      for (int j = 0; j < 4; ++j) {
        const float e = __expf(pv[n][j] - mrun[j]);
        pv[n][j] = e;
        rs[j] += e;
      }
#pragma unroll
    for (int j = 0; j < 4; ++j) {
      rs[j] += __shfl_xor(rs[j], 1);
      rs[j] += __shfl_xor(rs[j], 2);
      rs[j] += __shfl_xor(rs[j], 4);
      rs[j] += __shfl_xor(rs[j], 8);
      lrun[j] = lrun[j] * corr[j] + rs[j];
    }
#pragma unroll
    for (int n = 0; n < 4; ++n)
#pragma unroll
      for (int j = 0; j < 4; ++j) oacc[n][j] *= corr[j];
#pragma unroll
    for (int n = 0; n < 4; ++n)
#pragma unroll
      for (int j = 0; j < 4; ++j)
        Pw[((l >> 4) * 4 + j) * 80 + n * 16 + (l & 15)] = (short)f2b(pv[n][j]);
    __builtin_amdgcn_s_setprio(1);
#pragma unroll
    for (int kk2 = 0; kk2 < 2; ++kk2) {
      bf16x8 pf = *(const bf16x8*)(Pw + (l & 15) * 80 + kk2 * 32 + (l >> 4) * 8);
#pragma unroll
      for (int n = 0; n < 4; ++n) {
        const int dr = n * 16 + (l & 15);
        bf16x8 vf = *(const bf16x8*)(Vsc + dr * 64 + (((kk2 * 4 + (l >> 4)) ^ (dr & 7)) * 8));
        oacc[n] = __builtin_amdgcn_mfma_f32_16x16x32_bf16(pf, vf, oacc[n], 0, 0, 0);
      }
    }
    __builtin_amdgcn_s_setprio(0);
    // ---- A-phase boundary: flush A output, reset state ----
    if (i == nA - 1) {
      writeout(qtA * 64);
#pragma unroll
      for (int n = 0; n < 4; ++n) oacc[n] = f32x4{0.f, 0.f, 0.f, 0.f};
#pragma unroll
      for (int j = 0; j < 4; ++j) { mrun[j] = -1e30f; lrun[j] = 0.f; }
    }
    // ---- write prefetched regs to the other buffer ----
    if (havenext) {
      const int nxt = cur ^ 1;
      *(int4v*)(&Ks[nxt][s0]) = kr0;
      *(int4v*)(&Ks[nxt][s1]) = kr1;
      *(int4v*)(&Vs[nxt][s0]) = vr0;
      *(int4v*)(&Vs[nxt][s1]) = vr1;
    }
    __syncthreads();
    cur ^= 1;
  }
  writeout(qtB * 64);
}

// ---------------- final: out = x1 + swish(g)*lin ----------------
__global__ __launch_bounds__(256) void k_final(const float* __restrict__ x1,
                                               const unsigned short* __restrict__ gl,
                                               const float* __restrict__ beta,
                                               float* __restrict__ out) {
  const int idx = blockIdx.x * 256 + threadIdx.x;
  const int e = idx * 4;
  const int m = e >> 10, d = e & 1023;
  const float bt = beta[0];
  ushort4 gu = *(const ushort4*)(gl + (size_t)m * 2048 + d);
  ushort4 lu = *(const ushort4*)(gl + (size_t)m * 2048 + 1024 + d);
  float4 xv = *(const float4*)(x1 + e);
  float g0 = b2f(gu.x), g1 = b2f(gu.y), g2 = b2f(gu.z), g3 = b2f(gu.w);
  float l0 = b2f(lu.x), l1 = b2f(lu.y), l2 = b2f(lu.z), l3 = b2f(lu.w);
  float4 r;
  r.x = xv.x + g0 / (1.f + __expf(-bt * g0)) * l0;
  r.y = xv.y + g1 / (1.f + __expf(-bt * g1)) * l1;
  r.z = xv.z + g2 / (1.f + __expf(-bt * g2)) * l2;
  r.w = xv.w + g3 / (1.f + __expf(-bt * g3)) * l3;
  *(float4*)(out + e) = r;
}

extern "C" void kernel_launch(void* const* d_in, const int* in_sizes, int n_in,
                              void* d_out, int out_size, void* d_ws, size_t ws_size,
                              hipStream_t stream) {
  (void)in_sizes; (void)n_in; (void)out_size; (void)ws_size;
  const float* x      = (const float*)d_in[0];
  const float* Wq     = (const float*)d_in[1];
  const float* Wk     = (const float*)d_in[2];
  const float* Wv     = (const float*)d_in[3];
  const float* Wo     = (const float*)d_in[4];
  const float* scale1 = (const float*)d_in[5];
  const float* scale2 = (const float*)d_in[6];
  const float* W1     = (const float*)d_in[7];
  const float* b1     = (const float*)d_in[8];
  const float* Wg     = (const float*)d_in[9];
  const float* bg     = (const float*)d_in[10];
  const float* Wl     = (const float*)d_in[11];
  const float* bl     = (const float*)d_in[12];
  const float* beta   = (const float*)d_in[13];
  float* out = (float*)d_out;

  char* ws = (char*)d_ws;
  float* sums         = (float*)ws;                       // 256 B (4 used)
  float* bgl          = (float*)(ws + 256);               // 2048 floats
  unsigned short* WT  = (unsigned short*)(ws + 16384);                 // 3M bf16 (6 MB)
  unsigned short* h   = (unsigned short*)(ws + 16384 + 6291456);       // 4M bf16 (8 MB)
  unsigned short* qkv = (unsigned short*)((char*)h + 8388608);         // 12M bf16 (24 MB)
  unsigned short* vt  = (unsigned short*)((char*)qkv + 25165824);      // 4M bf16 (8 MB)
  unsigned short* ob  = (unsigned short*)((char*)vt + 8388608);        // 4M bf16 (8 MB)
  float* x1           = (float*)((char*)ob + 8388608);                 // 4M fp32 (16 MB)
  unsigned short* t1  = qkv;                 // reuse (qkv dead after attention)
  unsigned short* gl  = qkv + 4194304;       // reuse, 8M bf16

  hipMemsetAsync(sums, 0, 256, stream);

  // --- attention sublayer ---
  k_transpose_w<<<dim3(32, 32), 256, 0, stream>>>(Wq, WT);
  k_transpose_w<<<dim3(32, 32), 256, 0, stream>>>(Wk, WT + 1048576);
  k_transpose_w<<<dim3(32, 32), 256, 0, stream>>>(Wv, WT + 2097152);
  k_reduce_sq<<<dim3(256, 2), 256, 0, stream>>>(x, sums);
  k_rmsnorm<<<4096, 256, 0, stream>>>(x, scale1, sums, h);
  k_gemm<0, 4><<<dim3(24, 32), 256, 0, stream>>>(h, WT, (void*)qkv, nullptr, 3072, nullptr);
  k_rope<<<24576, 256, 0, stream>>>((unsigned int*)qkv);
  k_transpose_v<<<dim3(2, 64, 32), 256, 0, stream>>>(qkv, vt);
  k_attn<<<dim3(16, 16, 2), 256, 0, stream>>>(qkv, vt, ob);
  k_transpose_w<<<dim3(32, 32), 256, 0, stream>>>(Wo, WT);
  k_gemm<1, 2><<<dim3(16, 32), 256, 0, stream>>>(ob, WT, (void*)x1, x, 1024, sums + 2);

  // --- FFN sublayer (sums[2..3] filled by fused GEMM epilogue) ---
  k_rmsnorm<<<4096, 256, 0, stream>>>(x1, scale2, sums + 2, h);
  k_transpose_w<<<dim3(32, 32), 256, 0, stream>>>(W1, WT);
  k_gemm<2, 2><<<dim3(16, 32), 256, 0, stream>>>(h, WT, (void*)t1, b1, 1024, nullptr);
  k_transpose_w<<<dim3(32, 32), 256, 0, stream>>>(Wg, WT);
  k_transpose_w<<<dim3(32, 32), 256, 0, stream>>>(Wl, WT + 1048576);
  hipMemcpyAsync(bgl, bg, 4096, hipMemcpyDeviceToDevice, stream);
  hipMemcpyAsync(bgl + 1024, bl, 4096, hipMemcpyDeviceToDevice, stream);
  k_gemm<2, 4><<<dim3(16, 32), 256, 0, stream>>>(t1, WT, (void*)gl, bgl, 2048, nullptr);
  k_final<<<4096, 256, 0, stream>>>(x1, gl, beta, out);
}

// Round 10
// 367.801 us; speedup vs baseline: 1.1574x; 1.0746x over previous
//
#include <hip/hip_runtime.h>
#include <hip/hip_bf16.h>

typedef __attribute__((ext_vector_type(8))) short bf16x8;
typedef __attribute__((ext_vector_type(4))) float f32x4;
typedef __attribute__((ext_vector_type(4))) int int4v;

#define DEV static __device__ __forceinline__

DEV float b2f(unsigned short u) { union { unsigned int i; float f; } c; c.i = ((unsigned int)u) << 16; return c.f; }
DEV unsigned short f2b(float f) {
  __hip_bfloat16 h = __float2bfloat16(f);
  unsigned short u; __builtin_memcpy(&u, &h, 2); return u;
}

DEV void gload16(const void* g, void* l) {
  __builtin_amdgcn_global_load_lds(
      (const __attribute__((address_space(1))) unsigned int*)(g),
      (__attribute__((address_space(3))) unsigned int*)(l), 16, 0, 0);
}

// ---------------- all 7 weight transposes in one launch ----------------
__global__ __launch_bounds__(256) void k_transpose_w7(const float* __restrict__ Wq,
                                                      const float* __restrict__ Wk,
                                                      const float* __restrict__ Wv,
                                                      const float* __restrict__ Wo,
                                                      const float* __restrict__ W1,
                                                      const float* __restrict__ Wg,
                                                      const float* __restrict__ Wl,
                                                      unsigned short* __restrict__ WT) {
  __shared__ float tile[32][33];
  const float* W;
  switch (blockIdx.z) {
    case 0: W = Wq; break; case 1: W = Wk; break; case 2: W = Wv; break;
    case 3: W = Wo; break; case 4: W = W1; break; case 5: W = Wg; break;
    default: W = Wl; break;
  }
  unsigned short* dst = WT + (size_t)blockIdx.z * 1048576;
  const int tx = threadIdx.x & 31, ty = threadIdx.x >> 5;
  const int c0 = blockIdx.x * 32, r0 = blockIdx.y * 32;
#pragma unroll
  for (int i = 0; i < 4; ++i)
    tile[ty + i * 8][tx] = W[(size_t)(r0 + ty + i * 8) * 1024 + c0 + tx];
  __syncthreads();
#pragma unroll
  for (int i = 0; i < 4; ++i)
    dst[(size_t)(c0 + ty + i * 8) * 1024 + r0 + tx] = f2b(tile[tx][ty + i * 8]);
}

// ---------------- per-batch sum of squares ----------------
__global__ __launch_bounds__(256) void k_reduce_sq(const float* __restrict__ x,
                                                   float* __restrict__ sums) {
  const int b = blockIdx.y;
  const float4* xb = (const float4*)(x + (size_t)b * 2097152);
  float s = 0.f;
  for (int i = blockIdx.x * 256 + threadIdx.x; i < 524288; i += 256 * gridDim.x) {
    float4 v = xb[i];
    s += v.x * v.x + v.y * v.y + v.z * v.z + v.w * v.w;
  }
  __shared__ float red[256];
  red[threadIdx.x] = s;
  __syncthreads();
  for (int st = 128; st > 0; st >>= 1) {
    if (threadIdx.x < st) red[threadIdx.x] += red[threadIdx.x + st];
    __syncthreads();
  }
  if (threadIdx.x == 0) atomicAdd(&sums[b], red[0]);
}

// ---------------- rmsnorm ----------------
__global__ __launch_bounds__(256) void k_rmsnorm(const float* __restrict__ x,
                                                 const float* __restrict__ scale,
                                                 const float* __restrict__ sums,
                                                 unsigned short* __restrict__ out) {
  const int idx = blockIdx.x * 256 + threadIdx.x;
  const int e = idx * 4;
  const int m = e >> 10, d = e & 1023;
  const int b = m >> 11, s = m & 2047;
  const float inv = rsqrtf(sums[b] * (1.0f / 2097152.0f));
  float4 xv = *(const float4*)(x + (size_t)e);
  float4 sv = *(const float4*)(scale + (size_t)s * 1024 + d);
  ushort4 o;
  o.x = f2b(xv.x * sv.x * inv); o.y = f2b(xv.y * sv.y * inv);
  o.z = f2b(xv.z * sv.z * inv); o.w = f2b(xv.w * sv.w * inv);
  *(ushort4*)(out + e) = o;
}

// ---------------- GEMM: C[4096,N] = A[4096,1024] @ Bt[N,1024]^T ----------------
// EPI 0: bf16 store. EPI 1: fp32 (aux[row,col]+acc) + fused batch sumsq.
// EPI 2: bf16 (acc+aux[col]).  EPI 4: fused SwiGLU: B-tile = [Wg rows | Wl rows],
//        out = x1 + swish(g+bg)*(l+bl), fp32, N must be 1024.
template <int EPI, int NREP>
__global__ __launch_bounds__(256) void k_gemm(const unsigned short* __restrict__ A,
                                              const unsigned short* __restrict__ Bt,
                                              void* __restrict__ Cout,
                                              const float* __restrict__ aux,
                                              const float* __restrict__ aux2,
                                              const float* __restrict__ x1p,
                                              const float* __restrict__ betap,
                                              const int N,
                                              float* __restrict__ ss) {
  constexpr int BN = NREP * 32;
  __shared__ short As[128 * 64];
  __shared__ short Bs[BN * 64];
  const int tid = threadIdx.x;
  const int w = tid >> 6, l = tid & 63;
  const int brow = blockIdx.y * 128;
  const int bcol = blockIdx.x * (EPI == 4 ? 64 : BN);
  const int wr = (w >> 1) * 64;
  const int wc = (EPI == 4) ? (w & 1) * 32 : (w & 1) * (NREP * 16);
  const int lr = l >> 3, lg = l & 7;
  f32x4 acc[4][NREP] = {};
  const short* Ag = (const short*)A;
  const short* Bg = (const short*)Bt;
  for (int k0 = 0; k0 < 1024; k0 += 64) {
    __syncthreads();
#pragma unroll
    for (int p = 0; p < 4; ++p) {
      const int row = p * 32 + w * 8 + lr;
      gload16(Ag + (size_t)(brow + row) * 1024 + k0 + lg * 8,
              (char*)As + (size_t)(p * 32 + w * 8) * 128);
    }
#pragma unroll
    for (int p = 0; p < NREP; ++p) {
      const int row = p * 32 + w * 8 + lr;
      size_t goff;
      if (EPI == 4 && p >= 2)
        goff = (size_t)1048576 + (size_t)(bcol + row - 64) * 1024;  // Wl section
      else
        goff = (size_t)(bcol + row) * 1024;
      gload16(Bg + goff + k0 + lg * 8,
              (char*)Bs + (size_t)(p * 32 + w * 8) * 128);
    }
    __syncthreads();
#pragma unroll
    for (int kk = 0; kk < 2; ++kk) {
      const int g0 = kk * 4 + (l >> 4);
      bf16x8 af[4], bfr[NREP];
#pragma unroll
      for (int m = 0; m < 4; ++m)
        af[m] = *(const bf16x8*)(As + (wr + m * 16 + (l & 15)) * 64 + g0 * 8);
#pragma unroll
      for (int n = 0; n < NREP; ++n) {
        int bsrow;
        if (EPI == 4) bsrow = (n < 2) ? (wc + n * 16 + (l & 15)) : (64 + wc + (n - 2) * 16 + (l & 15));
        else bsrow = wc + n * 16 + (l & 15);
        bfr[n] = *(const bf16x8*)(Bs + bsrow * 64 + g0 * 8);
      }
#pragma unroll
      for (int m = 0; m < 4; ++m)
#pragma unroll
        for (int n = 0; n < NREP; ++n)
          acc[m][n] = __builtin_amdgcn_mfma_f32_16x16x32_bf16(af[m], bfr[n], acc[m][n], 0, 0, 0);
    }
  }
  const int rr = (l >> 4) * 4, cc = l & 15;
  if (EPI == 4) {
    const float bt = betap[0];
#pragma unroll
    for (int m = 0; m < 4; ++m)
#pragma unroll
      for (int nn = 0; nn < 2; ++nn) {
        const int col = bcol + wc + nn * 16 + cc;
#pragma unroll
        for (int j = 0; j < 4; ++j) {
          const int row = brow + wr + m * 16 + rr + j;
          const float gv = acc[m][nn][j] + aux[col];
          const float lv = acc[m][nn + 2][j] + aux2[col];
          const float sw = gv / (1.f + __expf(-bt * gv));
          ((float*)Cout)[(size_t)row * 1024 + col] = x1p[(size_t)row * 1024 + col] + sw * lv;
        }
      }
    return;
  }
  float sq = 0.f;
#pragma unroll
  for (int m = 0; m < 4; ++m)
#pragma unroll
    for (int n = 0; n < NREP; ++n) {
      const int col = bcol + wc + n * 16 + cc;
#pragma unroll
      for (int j = 0; j < 4; ++j) {
        const int row = brow + wr + m * 16 + rr + j;
        float v = acc[m][n][j];
        if (EPI == 0) {
          ((unsigned short*)Cout)[(size_t)row * N + col] = f2b(v);
        } else if (EPI == 1) {
          const float v2 = aux[(size_t)row * N + col] + v;
          ((float*)Cout)[(size_t)row * N + col] = v2;
          sq += v2 * v2;
        } else {
          ((unsigned short*)Cout)[(size_t)row * N + col] = f2b(v + aux[col]);
        }
      }
    }
  if (EPI == 1) {
#pragma unroll
    for (int off = 1; off < 64; off <<= 1) sq += __shfl_xor(sq, off);
    if (l == 0) atomicAdd(&ss[brow >> 11], sq);
  }
}

// ---------------- RoPE in place, 4 pairs per thread ----------------
__global__ __launch_bounds__(256) void k_rope(unsigned int* __restrict__ qkv32) {
  const int t = blockIdx.x * 256 + threadIdx.x;  // 1572864 total
  const int p0 = t * 4;
  const int m = p0 / 1536;
  const int pc0 = p0 - m * 1536;
  const int s = m & 2047;
  int4v v = *(const int4v*)(qkv32 + p0);
#pragma unroll
  for (int z = 0; z < 4; ++z) {
    const int i = (pc0 + z) & 511;
    const float theta = exp2f(-((float)i - 1.0f) * 0.0259525627f);
    const float ang = (float)s * theta;
    float sn, cs;
    __sincosf(ang, &sn, &cs);
    const unsigned int u = (unsigned int)v[z];
    const float xe = b2f((unsigned short)(u & 0xffffu));
    const float xo = b2f((unsigned short)(u >> 16));
    const float oe = xe * cs + xo * sn;
    const float oo = -xe * sn + xo * cs;
    v[z] = (int)((unsigned int)f2b(oe) | ((unsigned int)f2b(oo) << 16));
  }
  *(int4v*)(qkv32 + p0) = v;
}

// ---------------- V transpose ----------------
__global__ __launch_bounds__(256) void k_transpose_v(const unsigned short* __restrict__ qkv,
                                                     unsigned short* __restrict__ vt) {
  __shared__ unsigned short tile[32][33];
  const int tx = threadIdx.x & 31, ty = threadIdx.x >> 5;
  const int bh = blockIdx.z;
  const int b = bh >> 4, h = bh & 15;
  const int d0 = blockIdx.x * 32, s0 = blockIdx.y * 32;
#pragma unroll
  for (int i = 0; i < 4; ++i)
    tile[ty + i * 8][tx] = qkv[(size_t)(b * 2048 + s0 + ty + i * 8) * 3072 + 2048 + h * 64 + d0 + tx];
  __syncthreads();
#pragma unroll
  for (int i = 0; i < 4; ++i)
    vt[((size_t)bh * 64 + d0 + ty + i * 8) * 2048 + s0 + tx] = tile[tx][ty + i * 8];
}

// ---------------- flash attention v4: interleaved q-tile pair, log2-softmax ----------------
// grid 512 (XCD-grouped), 256 threads = 4 waves. Block handles qtA=p, qtB=31-p
// CONCURRENTLY per KV tile: two independent softmax chains (ILP), staging shared.
__global__ __launch_bounds__(256) void k_attn(const unsigned short* __restrict__ qkv,
                                              const unsigned short* __restrict__ vt,
                                              unsigned short* __restrict__ o) {
  __shared__ short Ks[2][4096];
  __shared__ short Vs[2][4096];
  __shared__ short Ps[8][1280];
  // XCD-grouped swizzle: all 16 pair-blocks of one (b,h) share id%8 -> same XCD L2.
  const int id = blockIdx.x;
  const int xcd = id & 7, q = id >> 3;
  const int p = q & 15, g = (q >> 4) * 8 + xcd;
  const int h = g & 15, b = g >> 4;
  const int qtA = p, qtB = 31 - p;
  const int nA = qtA + 1, nB = qtB + 1;  // nA <= 16 <= nB
  const int tid = threadIdx.x, w = tid >> 6, l = tid & 63;
  const int cc = l & 15, hi = l >> 4;
  const int qwA = qtA * 64 + w * 16, qwB = qtB * 64 + w * 16;
  const short* qg = (const short*)qkv;
  bf16x8 aqA0, aqA1, aqB0, aqB1;
  {
    const short* baseA = qg + (size_t)(b * 2048 + qwA + cc) * 3072 + h * 64 + hi * 8;
    aqA0 = *(const bf16x8*)baseA;
    aqA1 = *(const bf16x8*)(baseA + 32);
    const short* baseB = qg + (size_t)(b * 2048 + qwB + cc) * 3072 + h * 64 + hi * 8;
    aqB0 = *(const bf16x8*)baseB;
    aqB1 = *(const bf16x8*)(baseB + 32);
  }
  const float slope2 = exp2f(-0.5f * (float)(h + 1)) * 1.44269504f;  // log2 domain
  const float C1 = 0.125f * 1.44269504f;
  bf16x8 onesf;
#pragma unroll
  for (int z = 0; z < 8; ++z) onesf[z] = (short)0x3F80;  // bf16 1.0
  f32x4 oaccA[4] = {}, oaccB[4] = {};
  f32x4 rsA = {}, rsB = {};
  float mA[4] = {-1e30f, -1e30f, -1e30f, -1e30f};
  float mB[4] = {-1e30f, -1e30f, -1e30f, -1e30f};
  short* PwA = &Ps[w][0];
  short* PwB = &Ps[w + 4][0];
  const int c0 = tid, c1 = tid + 256;
  const int r0 = c0 >> 3, g0c = c0 & 7;
  const int r1 = c1 >> 3, g1c = c1 & 7;
  const int s0 = r0 * 64 + ((g0c ^ (r0 & 7)) * 8);
  const int s1 = r1 * 64 + ((g1c ^ (r1 & 7)) * 8);
  const short* kbase = qg + (size_t)(b * 2048) * 3072 + 1024 + h * 64;
  const short* vbase = (const short*)vt + (size_t)(b * 16 + h) * 64 * 2048;
  // prologue: stage tile 0
  *(int4v*)(&Ks[0][s0]) = *(const int4v*)(kbase + (size_t)r0 * 3072 + g0c * 8);
  *(int4v*)(&Ks[0][s1]) = *(const int4v*)(kbase + (size_t)r1 * 3072 + g1c * 8);
  *(int4v*)(&Vs[0][s0]) = *(const int4v*)(vbase + (size_t)r0 * 2048 + g0c * 8);
  *(int4v*)(&Vs[0][s1]) = *(const int4v*)(vbase + (size_t)r1 * 2048 + g1c * 8);
  __syncthreads();

  auto sm_pv = [&](f32x4 (&sacc)[4], f32x4 (&oacc)[4], f32x4& rs, float (&mr)[4],
                   short* Pw, const int qw, const bool domask, const int kv0,
                   const short* Vsc) {
    float alib[4];
#pragma unroll
    for (int n = 0; n < 4; ++n) alib[n] = slope2 * (float)(kv0 + n * 16 + cc);
    float sc[4][4], rm4[4];
#pragma unroll
    for (int j = 0; j < 4; ++j) rm4[j] = -3e30f;
#pragma unroll
    for (int n = 0; n < 4; ++n)
#pragma unroll
      for (int j = 0; j < 4; ++j) {
        float v = fmaf(sacc[n][j], C1, alib[n]);
        if (domask) {
          const int kvg = kv0 + n * 16 + cc;
          const int qrow = qw + hi * 4 + j;
          v = (kvg <= qrow) ? v : -1e30f;
        }
        sc[n][j] = v;
        rm4[j] = fmaxf(rm4[j], v);
      }
#pragma unroll
    for (int j = 0; j < 4; ++j) {
      rm4[j] = fmaxf(rm4[j], __shfl_xor(rm4[j], 1));
      rm4[j] = fmaxf(rm4[j], __shfl_xor(rm4[j], 2));
      rm4[j] = fmaxf(rm4[j], __shfl_xor(rm4[j], 4));
      rm4[j] = fmaxf(rm4[j], __shfl_xor(rm4[j], 8));
    }
    float corr[4];
#pragma unroll
    for (int j = 0; j < 4; ++j) {
      const float mn = fmaxf(mr[j], rm4[j]);
      corr[j] = exp2f(mr[j] - mn);
      mr[j] = mn;
    }
#pragma unroll
    for (int n = 0; n < 4; ++n)
#pragma unroll
      for (int j = 0; j < 4; ++j)
        Pw[(hi * 4 + j) * 80 + n * 16 + cc] = (short)f2b(exp2f(sc[n][j] - mr[j]));
#pragma unroll
    for (int n = 0; n < 4; ++n)
#pragma unroll
      for (int j = 0; j < 4; ++j) oacc[n][j] *= corr[j];
#pragma unroll
    for (int j = 0; j < 4; ++j) rs[j] *= corr[j];
    __builtin_amdgcn_s_setprio(1);
#pragma unroll
    for (int kk2 = 0; kk2 < 2; ++kk2) {
      bf16x8 pf = *(const bf16x8*)(Pw + cc * 80 + kk2 * 32 + hi * 8);
      rs = __builtin_amdgcn_mfma_f32_16x16x32_bf16(pf, onesf, rs, 0, 0, 0);
#pragma unroll
      for (int n = 0; n < 4; ++n) {
        const int dr = n * 16 + cc;
        bf16x8 vf = *(const bf16x8*)(Vsc + dr * 64 + (((kk2 * 4 + hi) ^ (dr & 7)) * 8));
        oacc[n] = __builtin_amdgcn_mfma_f32_16x16x32_bf16(pf, vf, oacc[n], 0, 0, 0);
      }
    }
    __builtin_amdgcn_s_setprio(0);
  };

  int cur = 0;
  for (int t = 0; t < nB; ++t) {
    int4v kr0, kr1, vr0, vr1;
    const bool havenext = (t + 1 < nB);
    if (havenext) {
      const size_t k0n = (size_t)(t + 1) * 64;
      kr0 = *(const int4v*)(kbase + (k0n + r0) * 3072 + g0c * 8);
      kr1 = *(const int4v*)(kbase + (k0n + r1) * 3072 + g1c * 8);
      vr0 = *(const int4v*)(vbase + (size_t)r0 * 2048 + k0n + g0c * 8);
      vr1 = *(const int4v*)(vbase + (size_t)r1 * 2048 + k0n + g1c * 8);
    }
    const int kv0 = t * 64;
    const short* Ksc = &Ks[cur][0];
    const short* Vsc = &Vs[cur][0];
    const bool doA = (t < nA);
    f32x4 sB[4] = {}, sA[4] = {};
    __builtin_amdgcn_s_setprio(1);
#pragma unroll
    for (int kk = 0; kk < 2; ++kk) {
      const int g0r = kk * 4 + hi;
      const bf16x8 aqk = kk ? aqB1 : aqB0;
#pragma unroll
      for (int n = 0; n < 4; ++n) {
        const int col = n * 16 + cc;
        bf16x8 bk = *(const bf16x8*)(Ksc + col * 64 + ((g0r ^ (col & 7)) * 8));
        sB[n] = __builtin_amdgcn_mfma_f32_16x16x32_bf16(aqk, bk, sB[n], 0, 0, 0);
      }
    }
    if (doA) {
#pragma unroll
      for (int kk = 0; kk < 2; ++kk) {
        const int g0r = kk * 4 + hi;
        const bf16x8 aqk = kk ? aqA1 : aqA0;
#pragma unroll
        for (int n = 0; n < 4; ++n) {
          const int col = n * 16 + cc;
          bf16x8 bk = *(const bf16x8*)(Ksc + col * 64 + ((g0r ^ (col & 7)) * 8));
          sA[n] = __builtin_amdgcn_mfma_f32_16x16x32_bf16(aqk, bk, sA[n], 0, 0, 0);
        }
      }
    }
    __builtin_amdgcn_s_setprio(0);
    sm_pv(sB, oaccB, rsB, mB, PwB, qwB, t == nB - 1, kv0, Vsc);
    if (doA) sm_pv(sA, oaccA, rsA, mA, PwA, qwA, t == nA - 1, kv0, Vsc);
    if (havenext) {
      const int nxt = cur ^ 1;
      *(int4v*)(&Ks[nxt][s0]) = kr0;
      *(int4v*)(&Ks[nxt][s1]) = kr1;
      *(int4v*)(&Vs[nxt][s0]) = vr0;
      *(int4v*)(&Vs[nxt][s1]) = vr1;
    }
    __syncthreads();
    cur ^= 1;
  }
  {
    const int rr = hi * 4;
#pragma unroll
    for (int n = 0; n < 4; ++n)
#pragma unroll
      for (int j = 0; j < 4; ++j) {
        const int row = qwA + rr + j;
        o[(size_t)(b * 2048 + row) * 1024 + h * 64 + n * 16 + cc] = f2b(oaccA[n][j] / rsA[j]);
      }
#pragma unroll
    for (int n = 0; n < 4; ++n)
#pragma unroll
      for (int j = 0; j < 4; ++j) {
        const int row = qwB + rr + j;
        o[(size_t)(b * 2048 + row) * 1024 + h * 64 + n * 16 + cc] = f2b(oaccB[n][j] / rsB[j]);
      }
  }
}

extern "C" void kernel_launch(void* const* d_in, const int* in_sizes, int n_in,
                              void* d_out, int out_size, void* d_ws, size_t ws_size,
                              hipStream_t stream) {
  (void)in_sizes; (void)n_in; (void)out_size; (void)ws_size;
  const float* x      = (const float*)d_in[0];
  const float* Wq     = (const float*)d_in[1];
  const float* Wk     = (const float*)d_in[2];
  const float* Wv     = (const float*)d_in[3];
  const float* Wo     = (const float*)d_in[4];
  const float* scale1 = (const float*)d_in[5];
  const float* scale2 = (const float*)d_in[6];
  const float* W1     = (const float*)d_in[7];
  const float* b1     = (const float*)d_in[8];
  const float* Wg     = (const float*)d_in[9];
  const float* bg     = (const float*)d_in[10];
  const float* Wl     = (const float*)d_in[11];
  const float* bl     = (const float*)d_in[12];
  const float* beta   = (const float*)d_in[13];
  float* out = (float*)d_out;

  char* ws = (char*)d_ws;
  float* sums         = (float*)ws;                                    // 256 B
  unsigned short* WT  = (unsigned short*)(ws + 16384);                 // 7M bf16 (14 MB)
  unsigned short* h   = (unsigned short*)(ws + 16384 + 14680064);      // 4M bf16 (8 MB)
  unsigned short* qkv = (unsigned short*)((char*)h + 8388608);         // 12M bf16 (24 MB)
  unsigned short* vt  = (unsigned short*)((char*)qkv + 25165824);      // 4M bf16 (8 MB)
  float* x1           = (float*)((char*)vt + 8388608);                 // 4M fp32 (16 MB)
  unsigned short* ob  = h;                   // reuse (h dead after qkv GEMM)
  unsigned short* t1  = qkv;                 // reuse (qkv dead after attention)

  hipMemsetAsync(sums, 0, 256, stream);

  // --- attention sublayer ---
  k_transpose_w7<<<dim3(32, 32, 7), 256, 0, stream>>>(Wq, Wk, Wv, Wo, W1, Wg, Wl, WT);
  k_reduce_sq<<<dim3(256, 2), 256, 0, stream>>>(x, sums);
  k_rmsnorm<<<4096, 256, 0, stream>>>(x, scale1, sums, h);
  k_gemm<0, 4><<<dim3(24, 32), 256, 0, stream>>>(h, WT, (void*)qkv, nullptr, nullptr, nullptr, nullptr, 3072, nullptr);
  k_rope<<<6144, 256, 0, stream>>>((unsigned int*)qkv);
  k_transpose_v<<<dim3(2, 64, 32), 256, 0, stream>>>(qkv, vt);
  k_attn<<<512, 256, 0, stream>>>(qkv, vt, ob);
  k_gemm<1, 2><<<dim3(16, 32), 256, 0, stream>>>(ob, WT + 3145728, (void*)x1, x, nullptr, nullptr, nullptr, 1024, sums + 2);

  // --- FFN sublayer (sums[2..3] filled by fused GEMM epilogue) ---
  k_rmsnorm<<<4096, 256, 0, stream>>>(x1, scale2, sums + 2, h);
  k_gemm<2, 2><<<dim3(16, 32), 256, 0, stream>>>(h, WT + 4194304, (void*)t1, b1, nullptr, nullptr, nullptr, 1024, nullptr);
  k_gemm<4, 4><<<dim3(16, 32), 256, 0, stream>>>(t1, WT + 5242880, (void*)out, bg, bl, x1, beta, 1024, nullptr);
}

// Round 11
// 361.650 us; speedup vs baseline: 1.1771x; 1.0170x over previous
//
#include <hip/hip_runtime.h>
#include <hip/hip_bf16.h>

typedef __attribute__((ext_vector_type(8))) short bf16x8;
typedef __attribute__((ext_vector_type(4))) float f32x4;
typedef __attribute__((ext_vector_type(4))) int int4v;

#define DEV static __device__ __forceinline__

DEV float b2f(unsigned short u) { union { unsigned int i; float f; } c; c.i = ((unsigned int)u) << 16; return c.f; }
DEV unsigned short f2b(float f) {
  __hip_bfloat16 h = __float2bfloat16(f);
  unsigned short u; __builtin_memcpy(&u, &h, 2); return u;
}

DEV void gload16(const void* g, void* l) {
  __builtin_amdgcn_global_load_lds(
      (const __attribute__((address_space(1))) unsigned int*)(g),
      (__attribute__((address_space(3))) unsigned int*)(l), 16, 0, 0);
}

// ---------------- all 7 weight transposes in one launch ----------------
__global__ __launch_bounds__(256) void k_transpose_w7(const float* __restrict__ Wq,
                                                      const float* __restrict__ Wk,
                                                      const float* __restrict__ Wv,
                                                      const float* __restrict__ Wo,
                                                      const float* __restrict__ W1,
                                                      const float* __restrict__ Wg,
                                                      const float* __restrict__ Wl,
                                                      unsigned short* __restrict__ WT) {
  __shared__ float tile[32][33];
  const float* W;
  switch (blockIdx.z) {
    case 0: W = Wq; break; case 1: W = Wk; break; case 2: W = Wv; break;
    case 3: W = Wo; break; case 4: W = W1; break; case 5: W = Wg; break;
    default: W = Wl; break;
  }
  unsigned short* dst = WT + (size_t)blockIdx.z * 1048576;
  const int tx = threadIdx.x & 31, ty = threadIdx.x >> 5;
  const int c0 = blockIdx.x * 32, r0 = blockIdx.y * 32;
#pragma unroll
  for (int i = 0; i < 4; ++i)
    tile[ty + i * 8][tx] = W[(size_t)(r0 + ty + i * 8) * 1024 + c0 + tx];
  __syncthreads();
#pragma unroll
  for (int i = 0; i < 4; ++i)
    dst[(size_t)(c0 + ty + i * 8) * 1024 + r0 + tx] = f2b(tile[tx][ty + i * 8]);
}

// ---------------- per-batch sum of squares ----------------
__global__ __launch_bounds__(256) void k_reduce_sq(const float* __restrict__ x,
                                                   float* __restrict__ sums) {
  const int b = blockIdx.y;
  const float4* xb = (const float4*)(x + (size_t)b * 2097152);
  float s = 0.f;
  for (int i = blockIdx.x * 256 + threadIdx.x; i < 524288; i += 256 * gridDim.x) {
    float4 v = xb[i];
    s += v.x * v.x + v.y * v.y + v.z * v.z + v.w * v.w;
  }
  __shared__ float red[256];
  red[threadIdx.x] = s;
  __syncthreads();
  for (int st = 128; st > 0; st >>= 1) {
    if (threadIdx.x < st) red[threadIdx.x] += red[threadIdx.x + st];
    __syncthreads();
  }
  if (threadIdx.x == 0) atomicAdd(&sums[b], red[0]);
}

// ---------------- rmsnorm ----------------
__global__ __launch_bounds__(256) void k_rmsnorm(const float* __restrict__ x,
                                                 const float* __restrict__ scale,
                                                 const float* __restrict__ sums,
                                                 unsigned short* __restrict__ out) {
  const int idx = blockIdx.x * 256 + threadIdx.x;
  const int e = idx * 4;
  const int m = e >> 10, d = e & 1023;
  const int b = m >> 11, s = m & 2047;
  const float inv = rsqrtf(sums[b] * (1.0f / 2097152.0f));
  float4 xv = *(const float4*)(x + (size_t)e);
  float4 sv = *(const float4*)(scale + (size_t)s * 1024 + d);
  ushort4 o;
  o.x = f2b(xv.x * sv.x * inv); o.y = f2b(xv.y * sv.y * inv);
  o.z = f2b(xv.z * sv.z * inv); o.w = f2b(xv.w * sv.w * inv);
  *(ushort4*)(out + e) = o;
}

// ---------------- GEMM: C[4096,N] = A[4096,1024] @ Bt[N,1024]^T ----------------
// EPI 1: fp32 (aux[row,col]+acc) + fused batch sumsq. EPI 2: bf16 (acc+aux[col]).
// EPI 4: fused SwiGLU: B-tile = [Wg rows | Wl rows], out = x1 + swish(g+bg)*(l+bl).
// EPI 5: bf16 store with fused RoPE for cols<2048 (Q,K sections of qkv).
template <int EPI, int NREP>
__global__ __launch_bounds__(256) void k_gemm(const unsigned short* __restrict__ A,
                                              const unsigned short* __restrict__ Bt,
                                              void* __restrict__ Cout,
                                              const float* __restrict__ aux,
                                              const float* __restrict__ aux2,
                                              const float* __restrict__ x1p,
                                              const float* __restrict__ betap,
                                              const int N,
                                              float* __restrict__ ss) {
  constexpr int BN = NREP * 32;
  __shared__ short As[128 * 64];
  __shared__ short Bs[BN * 64];
  const int tid = threadIdx.x;
  const int w = tid >> 6, l = tid & 63;
  const int brow = blockIdx.y * 128;
  const int bcol = blockIdx.x * (EPI == 4 ? 64 : BN);
  const int wr = (w >> 1) * 64;
  const int wc = (EPI == 4) ? (w & 1) * 32 : (w & 1) * (NREP * 16);
  const int lr = l >> 3, lg = l & 7;
  f32x4 acc[4][NREP] = {};
  const short* Ag = (const short*)A;
  const short* Bg = (const short*)Bt;
  for (int k0 = 0; k0 < 1024; k0 += 64) {
    __syncthreads();
#pragma unroll
    for (int p = 0; p < 4; ++p) {
      const int row = p * 32 + w * 8 + lr;
      gload16(Ag + (size_t)(brow + row) * 1024 + k0 + lg * 8,
              (char*)As + (size_t)(p * 32 + w * 8) * 128);
    }
#pragma unroll
    for (int p = 0; p < NREP; ++p) {
      const int row = p * 32 + w * 8 + lr;
      size_t goff;
      if (EPI == 4 && p >= 2)
        goff = (size_t)1048576 + (size_t)(bcol + row - 64) * 1024;  // Wl section
      else
        goff = (size_t)(bcol + row) * 1024;
      gload16(Bg + goff + k0 + lg * 8,
              (char*)Bs + (size_t)(p * 32 + w * 8) * 128);
    }
    __syncthreads();
#pragma unroll
    for (int kk = 0; kk < 2; ++kk) {
      const int g0 = kk * 4 + (l >> 4);
      bf16x8 af[4], bfr[NREP];
#pragma unroll
      for (int m = 0; m < 4; ++m)
        af[m] = *(const bf16x8*)(As + (wr + m * 16 + (l & 15)) * 64 + g0 * 8);
#pragma unroll
      for (int n = 0; n < NREP; ++n) {
        int bsrow;
        if (EPI == 4) bsrow = (n < 2) ? (wc + n * 16 + (l & 15)) : (64 + wc + (n - 2) * 16 + (l & 15));
        else bsrow = wc + n * 16 + (l & 15);
        bfr[n] = *(const bf16x8*)(Bs + bsrow * 64 + g0 * 8);
      }
#pragma unroll
      for (int m = 0; m < 4; ++m)
#pragma unroll
        for (int n = 0; n < NREP; ++n)
          acc[m][n] = __builtin_amdgcn_mfma_f32_16x16x32_bf16(af[m], bfr[n], acc[m][n], 0, 0, 0);
    }
  }
  const int rr = (l >> 4) * 4, cc = l & 15;
  if (EPI == 5) {
    const bool dorope = (bcol < 2048);   // block-uniform (128-col tiles align to 2048)
    if (dorope) {
      float th[NREP];
#pragma unroll
      for (int n = 0; n < NREP; ++n)
        th[n] = exp2f(-((float)(((bcol + wc + n * 16 + cc) & 1023) >> 1) - 1.0f) * 0.0259525627f);
#pragma unroll
      for (int m = 0; m < 4; ++m)
#pragma unroll
        for (int n = 0; n < NREP; ++n) {
          const int col = bcol + wc + n * 16 + cc;
#pragma unroll
          for (int j = 0; j < 4; ++j) {
            const int row = brow + wr + m * 16 + rr + j;
            const float vo = acc[m][n][j];
            const float vp = __shfl_xor(vo, 1);  // partner column (col^1)
            float sn, cs;
            __sincosf((float)(row & 2047) * th[n], &sn, &cs);
            // even d: oe = xe*cos + xo*sin; odd d: oo = -xe*sin + xo*cos
            const float r = (cc & 1) ? (cs * vo - sn * vp) : (cs * vo + sn * vp);
            ((unsigned short*)Cout)[(size_t)row * N + col] = f2b(r);
          }
        }
    } else {
#pragma unroll
      for (int m = 0; m < 4; ++m)
#pragma unroll
        for (int n = 0; n < NREP; ++n) {
          const int col = bcol + wc + n * 16 + cc;
#pragma unroll
          for (int j = 0; j < 4; ++j) {
            const int row = brow + wr + m * 16 + rr + j;
            ((unsigned short*)Cout)[(size_t)row * N + col] = f2b(acc[m][n][j]);
          }
        }
    }
    return;
  }
  if (EPI == 4) {
    const float bt = betap[0];
#pragma unroll
    for (int m = 0; m < 4; ++m)
#pragma unroll
      for (int nn = 0; nn < 2; ++nn) {
        const int col = bcol + wc + nn * 16 + cc;
#pragma unroll
        for (int j = 0; j < 4; ++j) {
          const int row = brow + wr + m * 16 + rr + j;
          const float gv = acc[m][nn][j] + aux[col];
          const float lv = acc[m][nn + 2][j] + aux2[col];
          const float sw = gv / (1.f + __expf(-bt * gv));
          ((float*)Cout)[(size_t)row * 1024 + col] = x1p[(size_t)row * 1024 + col] + sw * lv;
        }
      }
    return;
  }
  float sq = 0.f;
#pragma unroll
  for (int m = 0; m < 4; ++m)
#pragma unroll
    for (int n = 0; n < NREP; ++n) {
      const int col = bcol + wc + n * 16 + cc;
#pragma unroll
      for (int j = 0; j < 4; ++j) {
        const int row = brow + wr + m * 16 + rr + j;
        float v = acc[m][n][j];
        if (EPI == 1) {
          const float v2 = aux[(size_t)row * N + col] + v;
          ((float*)Cout)[(size_t)row * N + col] = v2;
          sq += v2 * v2;
        } else {
          ((unsigned short*)Cout)[(size_t)row * N + col] = f2b(v + aux[col]);
        }
      }
    }
  if (EPI == 1) {
#pragma unroll
    for (int off = 1; off < 64; off <<= 1) sq += __shfl_xor(sq, off);
    if (l == 0) atomicAdd(&ss[brow >> 11], sq);
  }
}

// ---------------- V transpose + fused RoPE on V ----------------
__global__ __launch_bounds__(256) void k_transpose_v(const unsigned short* __restrict__ qkv,
                                                     unsigned short* __restrict__ vt) {
  __shared__ unsigned short tile[32][33];
  const int tx = threadIdx.x & 31, ty = threadIdx.x >> 5;
  const int bh = blockIdx.z;
  const int b = bh >> 4, h = bh & 15;
  const int d0 = blockIdx.x * 32, s0 = blockIdx.y * 32;
#pragma unroll
  for (int i = 0; i < 4; ++i)
    tile[ty + i * 8][tx] = qkv[(size_t)(b * 2048 + s0 + ty + i * 8) * 3072 + 2048 + h * 64 + d0 + tx];
  __syncthreads();
  const float sv = (float)(s0 + tx);
  const int par = ty & 1;
#pragma unroll
  for (int i = 0; i < 4; ++i) {
    const int dsec = h * 64 + d0 + ty + i * 8;   // d within the 1024-wide V section
    const float th = exp2f(-((float)(dsec >> 1) - 1.0f) * 0.0259525627f);
    float sn, cs;
    __sincosf(sv * th, &sn, &cs);
    const float vo = b2f(tile[tx][ty + i * 8]);
    const float vp = b2f(tile[tx][(ty ^ 1) + i * 8]);  // partner d^1, same s
    const float r = par ? (cs * vo - sn * vp) : (cs * vo + sn * vp);
    vt[((size_t)bh * 64 + d0 + ty + i * 8) * 2048 + s0 + tx] = f2b(r);
  }
}

// ---------------- flash attention v4: interleaved q-tile pair, log2-softmax ----------------
// grid 512 (XCD-grouped), 256 threads = 4 waves. Block handles qtA=p, qtB=31-p
// CONCURRENTLY per KV tile: two independent softmax chains (ILP), staging shared.
__global__ __launch_bounds__(256) void k_attn(const unsigned short* __restrict__ qkv,
                                              const unsigned short* __restrict__ vt,
                                              unsigned short* __restrict__ o) {
  __shared__ short Ks[2][4096];
  __shared__ short Vs[2][4096];
  __shared__ short Ps[8][1280];
  const int id = blockIdx.x;
  const int xcd = id & 7, q = id >> 3;
  const int p = q & 15, g = (q >> 4) * 8 + xcd;
  const int h = g & 15, b = g >> 4;
  const int qtA = p, qtB = 31 - p;
  const int nA = qtA + 1, nB = qtB + 1;  // nA <= 16 <= nB
  const int tid = threadIdx.x, w = tid >> 6, l = tid & 63;
  const int cc = l & 15, hi = l >> 4;
  const int qwA = qtA * 64 + w * 16, qwB = qtB * 64 + w * 16;
  const short* qg = (const short*)qkv;
  bf16x8 aqA0, aqA1, aqB0, aqB1;
  {
    const short* baseA = qg + (size_t)(b * 2048 + qwA + cc) * 3072 + h * 64 + hi * 8;
    aqA0 = *(const bf16x8*)baseA;
    aqA1 = *(const bf16x8*)(baseA + 32);
    const short* baseB = qg + (size_t)(b * 2048 + qwB + cc) * 3072 + h * 64 + hi * 8;
    aqB0 = *(const bf16x8*)baseB;
    aqB1 = *(const bf16x8*)(baseB + 32);
  }
  const float slope2 = exp2f(-0.5f * (float)(h + 1)) * 1.44269504f;  // log2 domain
  const float C1 = 0.125f * 1.44269504f;
  bf16x8 onesf;
#pragma unroll
  for (int z = 0; z < 8; ++z) onesf[z] = (short)0x3F80;  // bf16 1.0
  f32x4 oaccA[4] = {}, oaccB[4] = {};
  f32x4 rsA = {}, rsB = {};
  float mA[4] = {-1e30f, -1e30f, -1e30f, -1e30f};
  float mB[4] = {-1e30f, -1e30f, -1e30f, -1e30f};
  short* PwA = &Ps[w][0];
  short* PwB = &Ps[w + 4][0];
  const int c0 = tid, c1 = tid + 256;
  const int r0 = c0 >> 3, g0c = c0 & 7;
  const int r1 = c1 >> 3, g1c = c1 & 7;
  const int s0 = r0 * 64 + ((g0c ^ (r0 & 7)) * 8);
  const int s1 = r1 * 64 + ((g1c ^ (r1 & 7)) * 8);
  const short* kbase = qg + (size_t)(b * 2048) * 3072 + 1024 + h * 64;
  const short* vbase = (const short*)vt + (size_t)(b * 16 + h) * 64 * 2048;
  // prologue: stage tile 0
  *(int4v*)(&Ks[0][s0]) = *(const int4v*)(kbase + (size_t)r0 * 3072 + g0c * 8);
  *(int4v*)(&Ks[0][s1]) = *(const int4v*)(kbase + (size_t)r1 * 3072 + g1c * 8);
  *(int4v*)(&Vs[0][s0]) = *(const int4v*)(vbase + (size_t)r0 * 2048 + g0c * 8);
  *(int4v*)(&Vs[0][s1]) = *(const int4v*)(vbase + (size_t)r1 * 2048 + g1c * 8);
  __syncthreads();

  auto sm_pv = [&](f32x4 (&sacc)[4], f32x4 (&oacc)[4], f32x4& rs, float (&mr)[4],
                   short* Pw, const int qw, const bool domask, const int kv0,
                   const short* Vsc) {
    float alib[4];
#pragma unroll
    for (int n = 0; n < 4; ++n) alib[n] = slope2 * (float)(kv0 + n * 16 + cc);
    float sc[4][4], rm4[4];
#pragma unroll
    for (int j = 0; j < 4; ++j) rm4[j] = -3e30f;
#pragma unroll
    for (int n = 0; n < 4; ++n)
#pragma unroll
      for (int j = 0; j < 4; ++j) {
        float v = fmaf(sacc[n][j], C1, alib[n]);
        if (domask) {
          const int kvg = kv0 + n * 16 + cc;
          const int qrow = qw + hi * 4 + j;
          v = (kvg <= qrow) ? v : -1e30f;
        }
        sc[n][j] = v;
        rm4[j] = fmaxf(rm4[j], v);
      }
#pragma unroll
    for (int j = 0; j < 4; ++j) {
      rm4[j] = fmaxf(rm4[j], __shfl_xor(rm4[j], 1));
      rm4[j] = fmaxf(rm4[j], __shfl_xor(rm4[j], 2));
      rm4[j] = fmaxf(rm4[j], __shfl_xor(rm4[j], 4));
      rm4[j] = fmaxf(rm4[j], __shfl_xor(rm4[j], 8));
    }
    float corr[4];
#pragma unroll
    for (int j = 0; j < 4; ++j) {
      const float mn = fmaxf(mr[j], rm4[j]);
      corr[j] = exp2f(mr[j] - mn);
      mr[j] = mn;
    }
#pragma unroll
    for (int n = 0; n < 4; ++n)
#pragma unroll
      for (int j = 0; j < 4; ++j)
        Pw[(hi * 4 + j) * 80 + n * 16 + cc] = (short)f2b(exp2f(sc[n][j] - mr[j]));
#pragma unroll
    for (int n = 0; n < 4; ++n)
#pragma unroll
      for (int j = 0; j < 4; ++j) oacc[n][j] *= corr[j];
#pragma unroll
    for (int j = 0; j < 4; ++j) rs[j] *= corr[j];
    __builtin_amdgcn_s_setprio(1);
#pragma unroll
    for (int kk2 = 0; kk2 < 2; ++kk2) {
      bf16x8 pf = *(const bf16x8*)(Pw + cc * 80 + kk2 * 32 + hi * 8);
      rs = __builtin_amdgcn_mfma_f32_16x16x32_bf16(pf, onesf, rs, 0, 0, 0);
#pragma unroll
      for (int n = 0; n < 4; ++n) {
        const int dr = n * 16 + cc;
        bf16x8 vf = *(const bf16x8*)(Vsc + dr * 64 + (((kk2 * 4 + hi) ^ (dr & 7)) * 8));
        oacc[n] = __builtin_amdgcn_mfma_f32_16x16x32_bf16(pf, vf, oacc[n], 0, 0, 0);
      }
    }
    __builtin_amdgcn_s_setprio(0);
  };

  int cur = 0;
  for (int t = 0; t < nB; ++t) {
    int4v kr0, kr1, vr0, vr1;
    const bool havenext = (t + 1 < nB);
    if (havenext) {
      const size_t k0n = (size_t)(t + 1) * 64;
      kr0 = *(const int4v*)(kbase + (k0n + r0) * 3072 + g0c * 8);
      kr1 = *(const int4v*)(kbase + (k0n + r1) * 3072 + g1c * 8);
      vr0 = *(const int4v*)(vbase + (size_t)r0 * 2048 + k0n + g0c * 8);
      vr1 = *(const int4v*)(vbase + (size_t)r1 * 2048 + k0n + g1c * 8);
    }
    const int kv0 = t * 64;
    const short* Ksc = &Ks[cur][0];
    const short* Vsc = &Vs[cur][0];
    const bool doA = (t < nA);
    f32x4 sB[4] = {}, sA[4] = {};
    __builtin_amdgcn_s_setprio(1);
#pragma unroll
    for (int kk = 0; kk < 2; ++kk) {
      const int g0r = kk * 4 + hi;
      const bf16x8 aqk = kk ? aqB1 : aqB0;
#pragma unroll
      for (int n = 0; n < 4; ++n) {
        const int col = n * 16 + cc;
        bf16x8 bk = *(const bf16x8*)(Ksc + col * 64 + ((g0r ^ (col & 7)) * 8));
        sB[n] = __builtin_amdgcn_mfma_f32_16x16x32_bf16(aqk, bk, sB[n], 0, 0, 0);
      }
    }
    if (doA) {
#pragma unroll
      for (int kk = 0; kk < 2; ++kk) {
        const int g0r = kk * 4 + hi;
        const bf16x8 aqk = kk ? aqA1 : aqA0;
#pragma unroll
        for (int n = 0; n < 4; ++n) {
          const int col = n * 16 + cc;
          bf16x8 bk = *(const bf16x8*)(Ksc + col * 64 + ((g0r ^ (col & 7)) * 8));
          sA[n] = __builtin_amdgcn_mfma_f32_16x16x32_bf16(aqk, bk, sA[n], 0, 0, 0);
        }
      }
    }
    __builtin_amdgcn_s_setprio(0);
    sm_pv(sB, oaccB, rsB, mB, PwB, qwB, t == nB - 1, kv0, Vsc);
    if (doA) sm_pv(sA, oaccA, rsA, mA, PwA, qwA, t == nA - 1, kv0, Vsc);
    if (havenext) {
      const int nxt = cur ^ 1;
      *(int4v*)(&Ks[nxt][s0]) = kr0;
      *(int4v*)(&Ks[nxt][s1]) = kr1;
      *(int4v*)(&Vs[nxt][s0]) = vr0;
      *(int4v*)(&Vs[nxt][s1]) = vr1;
    }
    __syncthreads();
    cur ^= 1;
  }
  {
    const int rr = hi * 4;
#pragma unroll
    for (int n = 0; n < 4; ++n)
#pragma unroll
      for (int j = 0; j < 4; ++j) {
        const int row = qwA + rr + j;
        o[(size_t)(b * 2048 + row) * 1024 + h * 64 + n * 16 + cc] = f2b(oaccA[n][j] / rsA[j]);
      }
#pragma unroll
    for (int n = 0; n < 4; ++n)
#pragma unroll
      for (int j = 0; j < 4; ++j) {
        const int row = qwB + rr + j;
        o[(size_t)(b * 2048 + row) * 1024 + h * 64 + n * 16 + cc] = f2b(oaccB[n][j] / rsB[j]);
      }
  }
}

extern "C" void kernel_launch(void* const* d_in, const int* in_sizes, int n_in,
                              void* d_out, int out_size, void* d_ws, size_t ws_size,
                              hipStream_t stream) {
  (void)in_sizes; (void)n_in; (void)out_size; (void)ws_size;
  const float* x      = (const float*)d_in[0];
  const float* Wq     = (const float*)d_in[1];
  const float* Wk     = (const float*)d_in[2];
  const float* Wv     = (const float*)d_in[3];
  const float* Wo     = (const float*)d_in[4];
  const float* scale1 = (const float*)d_in[5];
  const float* scale2 = (const float*)d_in[6];
  const float* W1     = (const float*)d_in[7];
  const float* b1     = (const float*)d_in[8];
  const float* Wg     = (const float*)d_in[9];
  const float* bg     = (const float*)d_in[10];
  const float* Wl     = (const float*)d_in[11];
  const float* bl     = (const float*)d_in[12];
  const float* beta   = (const float*)d_in[13];
  float* out = (float*)d_out;

  char* ws = (char*)d_ws;
  float* sums         = (float*)ws;                                    // 256 B
  unsigned short* WT  = (unsigned short*)(ws + 16384);                 // 7M bf16 (14 MB)
  unsigned short* h   = (unsigned short*)(ws + 16384 + 14680064);      // 4M bf16 (8 MB)
  unsigned short* qkv = (unsigned short*)((char*)h + 8388608);         // 12M bf16 (24 MB)
  unsigned short* vt  = (unsigned short*)((char*)qkv + 25165824);      // 4M bf16 (8 MB)
  float* x1           = (float*)((char*)vt + 8388608);                 // 4M fp32 (16 MB)
  unsigned short* ob  = h;                   // reuse (h dead after qkv GEMM)
  unsigned short* t1  = qkv;                 // reuse (qkv dead after attention)

  hipMemsetAsync(sums, 0, 256, stream);

  // --- attention sublayer ---
  k_transpose_w7<<<dim3(32, 32, 7), 256, 0, stream>>>(Wq, Wk, Wv, Wo, W1, Wg, Wl, WT);
  k_reduce_sq<<<dim3(256, 2), 256, 0, stream>>>(x, sums);
  k_rmsnorm<<<4096, 256, 0, stream>>>(x, scale1, sums, h);
  k_gemm<5, 4><<<dim3(24, 32), 256, 0, stream>>>(h, WT, (void*)qkv, nullptr, nullptr, nullptr, nullptr, 3072, nullptr);
  k_transpose_v<<<dim3(2, 64, 32), 256, 0, stream>>>(qkv, vt);
  k_attn<<<512, 256, 0, stream>>>(qkv, vt, ob);
  k_gemm<1, 2><<<dim3(16, 32), 256, 0, stream>>>(ob, WT + 3145728, (void*)x1, x, nullptr, nullptr, nullptr, 1024, sums + 2);

  // --- FFN sublayer (sums[2..3] filled by fused GEMM epilogue) ---
  k_rmsnorm<<<4096, 256, 0, stream>>>(x1, scale2, sums + 2, h);
  k_gemm<2, 2><<<dim3(16, 32), 256, 0, stream>>>(h, WT + 4194304, (void*)t1, b1, nullptr, nullptr, nullptr, 1024, nullptr);
  k_gemm<4, 4><<<dim3(16, 32), 256, 0, stream>>>(t1, WT + 5242880, (void*)out, bg, bl, x1, beta, 1024, nullptr);
}

// Round 12
// 351.161 us; speedup vs baseline: 1.2122x; 1.0299x over previous
//
#include <hip/hip_runtime.h>
#include <hip/hip_bf16.h>

typedef __attribute__((ext_vector_type(8))) short bf16x8;
typedef __attribute__((ext_vector_type(4))) float f32x4;
typedef __attribute__((ext_vector_type(4))) int int4v;

#define DEV static __device__ __forceinline__

DEV float b2f(unsigned short u) { union { unsigned int i; float f; } c; c.i = ((unsigned int)u) << 16; return c.f; }
DEV unsigned short f2b(float f) {
  __hip_bfloat16 h = __float2bfloat16(f);
  unsigned short u; __builtin_memcpy(&u, &h, 2); return u;
}

DEV void gload16(const void* g, void* l) {
  __builtin_amdgcn_global_load_lds(
      (const __attribute__((address_space(1))) unsigned int*)(g),
      (__attribute__((address_space(3))) unsigned int*)(l), 16, 0, 0);
}

// ---------------- all 7 weight transposes in one launch ----------------
__global__ __launch_bounds__(256) void k_transpose_w7(const float* __restrict__ Wq,
                                                      const float* __restrict__ Wk,
                                                      const float* __restrict__ Wv,
                                                      const float* __restrict__ Wo,
                                                      const float* __restrict__ W1,
                                                      const float* __restrict__ Wg,
                                                      const float* __restrict__ Wl,
                                                      unsigned short* __restrict__ WT) {
  __shared__ float tile[32][33];
  const float* W;
  switch (blockIdx.z) {
    case 0: W = Wq; break; case 1: W = Wk; break; case 2: W = Wv; break;
    case 3: W = Wo; break; case 4: W = W1; break; case 5: W = Wg; break;
    default: W = Wl; break;
  }
  unsigned short* dst = WT + (size_t)blockIdx.z * 1048576;
  const int tx = threadIdx.x & 31, ty = threadIdx.x >> 5;
  const int c0 = blockIdx.x * 32, r0 = blockIdx.y * 32;
#pragma unroll
  for (int i = 0; i < 4; ++i)
    tile[ty + i * 8][tx] = W[(size_t)(r0 + ty + i * 8) * 1024 + c0 + tx];
  __syncthreads();
#pragma unroll
  for (int i = 0; i < 4; ++i)
    dst[(size_t)(c0 + ty + i * 8) * 1024 + r0 + tx] = f2b(tile[tx][ty + i * 8]);
}

// ---------------- per-batch sum of squares ----------------
__global__ __launch_bounds__(256) void k_reduce_sq(const float* __restrict__ x,
                                                   float* __restrict__ sums) {
  const int b = blockIdx.y;
  const float4* xb = (const float4*)(x + (size_t)b * 2097152);
  float s = 0.f;
  for (int i = blockIdx.x * 256 + threadIdx.x; i < 524288; i += 256 * gridDim.x) {
    float4 v = xb[i];
    s += v.x * v.x + v.y * v.y + v.z * v.z + v.w * v.w;
  }
  __shared__ float red[256];
  red[threadIdx.x] = s;
  __syncthreads();
  for (int st = 128; st > 0; st >>= 1) {
    if (threadIdx.x < st) red[threadIdx.x] += red[threadIdx.x + st];
    __syncthreads();
  }
  if (threadIdx.x == 0) atomicAdd(&sums[b], red[0]);
}

// ---------------- rmsnorm ----------------
__global__ __launch_bounds__(256) void k_rmsnorm(const float* __restrict__ x,
                                                 const float* __restrict__ scale,
                                                 const float* __restrict__ sums,
                                                 unsigned short* __restrict__ out) {
  const int idx = blockIdx.x * 256 + threadIdx.x;
  const int e = idx * 4;
  const int m = e >> 10, d = e & 1023;
  const int b = m >> 11, s = m & 2047;
  const float inv = rsqrtf(sums[b] * (1.0f / 2097152.0f));
  float4 xv = *(const float4*)(x + (size_t)e);
  float4 sv = *(const float4*)(scale + (size_t)s * 1024 + d);
  ushort4 o;
  o.x = f2b(xv.x * sv.x * inv); o.y = f2b(xv.y * sv.y * inv);
  o.z = f2b(xv.z * sv.z * inv); o.w = f2b(xv.w * sv.w * inv);
  *(ushort4*)(out + e) = o;
}

// ---------------- GEMM: C[4096,N] = A[4096,1024] @ Bt[N,1024]^T ----------------
// EPI 1: fp32 (aux[row,col]+acc) + fused batch sumsq. EPI 2: bf16 (acc+aux[col]).
// EPI 4: fused SwiGLU: B-tile = [Wg rows | Wl rows], out = x1 + swish(g+bg)*(l+bl).
// EPI 5: bf16 store with fused RoPE for cols<2048 (Q,K sections of qkv).
template <int EPI, int NREP>
__global__ __launch_bounds__(256) void k_gemm(const unsigned short* __restrict__ A,
                                              const unsigned short* __restrict__ Bt,
                                              void* __restrict__ Cout,
                                              const float* __restrict__ aux,
                                              const float* __restrict__ aux2,
                                              const float* __restrict__ x1p,
                                              const float* __restrict__ betap,
                                              const int N,
                                              float* __restrict__ ss) {
  constexpr int BN = NREP * 32;
  __shared__ short As[128 * 64];
  __shared__ short Bs[BN * 64];
  const int tid = threadIdx.x;
  const int w = tid >> 6, l = tid & 63;
  const int brow = blockIdx.y * 128;
  const int bcol = blockIdx.x * (EPI == 4 ? 64 : BN);
  const int wr = (w >> 1) * 64;
  const int wc = (EPI == 4) ? (w & 1) * 32 : (w & 1) * (NREP * 16);
  const int lr = l >> 3, lg = l & 7;
  f32x4 acc[4][NREP] = {};
  const short* Ag = (const short*)A;
  const short* Bg = (const short*)Bt;
  for (int k0 = 0; k0 < 1024; k0 += 64) {
    __syncthreads();
#pragma unroll
    for (int p = 0; p < 4; ++p) {
      const int row = p * 32 + w * 8 + lr;
      gload16(Ag + (size_t)(brow + row) * 1024 + k0 + lg * 8,
              (char*)As + (size_t)(p * 32 + w * 8) * 128);
    }
#pragma unroll
    for (int p = 0; p < NREP; ++p) {
      const int row = p * 32 + w * 8 + lr;
      size_t goff;
      if (EPI == 4 && p >= 2)
        goff = (size_t)1048576 + (size_t)(bcol + row - 64) * 1024;  // Wl section
      else
        goff = (size_t)(bcol + row) * 1024;
      gload16(Bg + goff + k0 + lg * 8,
              (char*)Bs + (size_t)(p * 32 + w * 8) * 128);
    }
    __syncthreads();
#pragma unroll
    for (int kk = 0; kk < 2; ++kk) {
      const int g0 = kk * 4 + (l >> 4);
      bf16x8 af[4], bfr[NREP];
#pragma unroll
      for (int m = 0; m < 4; ++m)
        af[m] = *(const bf16x8*)(As + (wr + m * 16 + (l & 15)) * 64 + g0 * 8);
#pragma unroll
      for (int n = 0; n < NREP; ++n) {
        int bsrow;
        if (EPI == 4) bsrow = (n < 2) ? (wc + n * 16 + (l & 15)) : (64 + wc + (n - 2) * 16 + (l & 15));
        else bsrow = wc + n * 16 + (l & 15);
        bfr[n] = *(const bf16x8*)(Bs + bsrow * 64 + g0 * 8);
      }
#pragma unroll
      for (int m = 0; m < 4; ++m)
#pragma unroll
        for (int n = 0; n < NREP; ++n)
          acc[m][n] = __builtin_amdgcn_mfma_f32_16x16x32_bf16(af[m], bfr[n], acc[m][n], 0, 0, 0);
    }
  }
  const int rr = (l >> 4) * 4, cc = l & 15;
  if (EPI == 5) {
    const bool dorope = (bcol < 2048);   // block-uniform (128-col tiles align to 2048)
    if (dorope) {
      float th[NREP];
#pragma unroll
      for (int n = 0; n < NREP; ++n)
        th[n] = exp2f(-((float)(((bcol + wc + n * 16 + cc) & 1023) >> 1) - 1.0f) * 0.0259525627f);
#pragma unroll
      for (int m = 0; m < 4; ++m)
#pragma unroll
        for (int n = 0; n < NREP; ++n) {
          const int col = bcol + wc + n * 16 + cc;
#pragma unroll
          for (int j = 0; j < 4; ++j) {
            const int row = brow + wr + m * 16 + rr + j;
            const float vo = acc[m][n][j];
            const float vp = __shfl_xor(vo, 1);  // partner column (col^1)
            float sn, cs;
            __sincosf((float)(row & 2047) * th[n], &sn, &cs);
            const float r = (cc & 1) ? (cs * vo - sn * vp) : (cs * vo + sn * vp);
            ((unsigned short*)Cout)[(size_t)row * N + col] = f2b(r);
          }
        }
    } else {
#pragma unroll
      for (int m = 0; m < 4; ++m)
#pragma unroll
        for (int n = 0; n < NREP; ++n) {
          const int col = bcol + wc + n * 16 + cc;
#pragma unroll
          for (int j = 0; j < 4; ++j) {
            const int row = brow + wr + m * 16 + rr + j;
            ((unsigned short*)Cout)[(size_t)row * N + col] = f2b(acc[m][n][j]);
          }
        }
    }
    return;
  }
  if (EPI == 4) {
    const float bt = betap[0];
#pragma unroll
    for (int m = 0; m < 4; ++m)
#pragma unroll
      for (int nn = 0; nn < 2; ++nn) {
        const int col = bcol + wc + nn * 16 + cc;
#pragma unroll
        for (int j = 0; j < 4; ++j) {
          const int row = brow + wr + m * 16 + rr + j;
          const float gv = acc[m][nn][j] + aux[col];
          const float lv = acc[m][nn + 2][j] + aux2[col];
          const float sw = gv / (1.f + __expf(-bt * gv));
          ((float*)Cout)[(size_t)row * 1024 + col] = x1p[(size_t)row * 1024 + col] + sw * lv;
        }
      }
    return;
  }
  float sq = 0.f;
#pragma unroll
  for (int m = 0; m < 4; ++m)
#pragma unroll
    for (int n = 0; n < NREP; ++n) {
      const int col = bcol + wc + n * 16 + cc;
#pragma unroll
      for (int j = 0; j < 4; ++j) {
        const int row = brow + wr + m * 16 + rr + j;
        float v = acc[m][n][j];
        if (EPI == 1) {
          const float v2 = aux[(size_t)row * N + col] + v;
          ((float*)Cout)[(size_t)row * N + col] = v2;
          sq += v2 * v2;
        } else {
          ((unsigned short*)Cout)[(size_t)row * N + col] = f2b(v + aux[col]);
        }
      }
    }
  if (EPI == 1) {
#pragma unroll
    for (int off = 1; off < 64; off <<= 1) sq += __shfl_xor(sq, off);
    if (l == 0) atomicAdd(&ss[brow >> 11], sq);
  }
}

// ---------------- V transpose + fused RoPE on V ----------------
__global__ __launch_bounds__(256) void k_transpose_v(const unsigned short* __restrict__ qkv,
                                                     unsigned short* __restrict__ vt) {
  __shared__ unsigned short tile[32][33];
  const int tx = threadIdx.x & 31, ty = threadIdx.x >> 5;
  const int bh = blockIdx.z;
  const int b = bh >> 4, h = bh & 15;
  const int d0 = blockIdx.x * 32, s0 = blockIdx.y * 32;
#pragma unroll
  for (int i = 0; i < 4; ++i)
    tile[ty + i * 8][tx] = qkv[(size_t)(b * 2048 + s0 + ty + i * 8) * 3072 + 2048 + h * 64 + d0 + tx];
  __syncthreads();
  const float sv = (float)(s0 + tx);
  const int par = ty & 1;
#pragma unroll
  for (int i = 0; i < 4; ++i) {
    const int dsec = h * 64 + d0 + ty + i * 8;   // d within the 1024-wide V section
    const float th = exp2f(-((float)(dsec >> 1) - 1.0f) * 0.0259525627f);
    float sn, cs;
    __sincosf(sv * th, &sn, &cs);
    const float vo = b2f(tile[tx][ty + i * 8]);
    const float vp = b2f(tile[tx][(ty ^ 1) + i * 8]);  // partner d^1, same s
    const float r = par ? (cs * vo - sn * vp) : (cs * vo + sn * vp);
    vt[((size_t)bh * 64 + d0 + ty + i * 8) * 2048 + s0 + tx] = f2b(r);
  }
}

// ---------------- flash attention v5: interleaved q-tile pair, NO-MAX softmax ----------------
// grid 512 (XCD-grouped), 256 threads = 4 waves. Block handles qtA=p, qtB=31-p.
// Scores use the full row-relative ALiBi term slope2*(kv-qrow) <= 0, and since
// |qk*C1| is bounded (~10 in log2 domain), P = exp2(sc) directly — no running max,
// no cross-lane reduce, no rescale. rs/oacc accumulate unnormalized; divide at end.
__global__ __launch_bounds__(256) void k_attn(const unsigned short* __restrict__ qkv,
                                              const unsigned short* __restrict__ vt,
                                              unsigned short* __restrict__ o) {
  __shared__ short Ks[2][4096];
  __shared__ short Vs[2][4096];
  __shared__ short Ps[8][1280];
  const int id = blockIdx.x;
  const int xcd = id & 7, q = id >> 3;
  const int p = q & 15, g = (q >> 4) * 8 + xcd;
  const int h = g & 15, b = g >> 4;
  const int qtA = p, qtB = 31 - p;
  const int nA = qtA + 1, nB = qtB + 1;  // nA <= 16 <= nB
  const int tid = threadIdx.x, w = tid >> 6, l = tid & 63;
  const int cc = l & 15, hi = l >> 4;
  const int qwA = qtA * 64 + w * 16, qwB = qtB * 64 + w * 16;
  const short* qg = (const short*)qkv;
  bf16x8 aqA0, aqA1, aqB0, aqB1;
  {
    const short* baseA = qg + (size_t)(b * 2048 + qwA + cc) * 3072 + h * 64 + hi * 8;
    aqA0 = *(const bf16x8*)baseA;
    aqA1 = *(const bf16x8*)(baseA + 32);
    const short* baseB = qg + (size_t)(b * 2048 + qwB + cc) * 3072 + h * 64 + hi * 8;
    aqB0 = *(const bf16x8*)baseB;
    aqB1 = *(const bf16x8*)(baseB + 32);
  }
  const float slope2 = exp2f(-0.5f * (float)(h + 1)) * 1.44269504f;  // log2 domain
  const float C1 = 0.125f * 1.44269504f;
  const float step = slope2 * 64.f;
  bf16x8 onesf;
#pragma unroll
  for (int z = 0; z < 8; ++z) onesf[z] = (short)0x3F80;  // bf16 1.0
  f32x4 oaccA[4] = {}, oaccB[4] = {};
  f32x4 rsA = {}, rsB = {};
  float baseA4[4], baseB4[4];
#pragma unroll
  for (int n = 0; n < 4; ++n) {
    baseA4[n] = slope2 * (float)(n * 16 + cc - qwA - hi * 4);
    baseB4[n] = slope2 * (float)(n * 16 + cc - qwB - hi * 4);
  }
  short* PwA = &Ps[w][0];
  short* PwB = &Ps[w + 4][0];
  const int c0 = tid, c1 = tid + 256;
  const int r0 = c0 >> 3, g0c = c0 & 7;
  const int r1 = c1 >> 3, g1c = c1 & 7;
  const int s0 = r0 * 64 + ((g0c ^ (r0 & 7)) * 8);
  const int s1 = r1 * 64 + ((g1c ^ (r1 & 7)) * 8);
  const short* kbase = qg + (size_t)(b * 2048) * 3072 + 1024 + h * 64;
  const short* vbase = (const short*)vt + (size_t)(b * 16 + h) * 64 * 2048;
  // prologue: stage tile 0
  *(int4v*)(&Ks[0][s0]) = *(const int4v*)(kbase + (size_t)r0 * 3072 + g0c * 8);
  *(int4v*)(&Ks[0][s1]) = *(const int4v*)(kbase + (size_t)r1 * 3072 + g1c * 8);
  *(int4v*)(&Vs[0][s0]) = *(const int4v*)(vbase + (size_t)r0 * 2048 + g0c * 8);
  *(int4v*)(&Vs[0][s1]) = *(const int4v*)(vbase + (size_t)r1 * 2048 + g1c * 8);
  __syncthreads();

  auto sm_pv = [&](f32x4 (&sacc)[4], f32x4 (&oacc)[4], f32x4& rs, float (&base)[4],
                   short* Pw, const int qw, const bool domask, const int kv0,
                   const short* Vsc) {
#pragma unroll
    for (int n = 0; n < 4; ++n) {
#pragma unroll
      for (int j = 0; j < 4; ++j) {
        float v = fmaf(sacc[n][j], C1, base[n] - slope2 * (float)j);
        if (domask) {
          const int kvg = kv0 + n * 16 + cc;
          const int qrow = qw + hi * 4 + j;
          if (kvg > qrow) v = -1e30f;   // exp2 -> 0
        }
        Pw[(hi * 4 + j) * 80 + n * 16 + cc] = (short)f2b(exp2f(v));
      }
      base[n] += step;
    }
    __builtin_amdgcn_s_setprio(1);
#pragma unroll
    for (int kk2 = 0; kk2 < 2; ++kk2) {
      bf16x8 pf = *(const bf16x8*)(Pw + cc * 80 + kk2 * 32 + hi * 8);
      rs = __builtin_amdgcn_mfma_f32_16x16x32_bf16(pf, onesf, rs, 0, 0, 0);
#pragma unroll
      for (int n = 0; n < 4; ++n) {
        const int dr = n * 16 + cc;
        bf16x8 vf = *(const bf16x8*)(Vsc + dr * 64 + (((kk2 * 4 + hi) ^ (dr & 7)) * 8));
        oacc[n] = __builtin_amdgcn_mfma_f32_16x16x32_bf16(pf, vf, oacc[n], 0, 0, 0);
      }
    }
    __builtin_amdgcn_s_setprio(0);
  };

  int cur = 0;
  for (int t = 0; t < nB; ++t) {
    int4v kr0, kr1, vr0, vr1;
    const bool havenext = (t + 1 < nB);
    if (havenext) {
      const size_t k0n = (size_t)(t + 1) * 64;
      kr0 = *(const int4v*)(kbase + (k0n + r0) * 3072 + g0c * 8);
      kr1 = *(const int4v*)(kbase + (k0n + r1) * 3072 + g1c * 8);
      vr0 = *(const int4v*)(vbase + (size_t)r0 * 2048 + k0n + g0c * 8);
      vr1 = *(const int4v*)(vbase + (size_t)r1 * 2048 + k0n + g1c * 8);
    }
    const int kv0 = t * 64;
    const short* Ksc = &Ks[cur][0];
    const short* Vsc = &Vs[cur][0];
    const bool doA = (t < nA);
    f32x4 sB[4] = {}, sA[4] = {};
    __builtin_amdgcn_s_setprio(1);
#pragma unroll
    for (int kk = 0; kk < 2; ++kk) {
      const int g0r = kk * 4 + hi;
      const bf16x8 aqk = kk ? aqB1 : aqB0;
#pragma unroll
      for (int n = 0; n < 4; ++n) {
        const int col = n * 16 + cc;
        bf16x8 bk = *(const bf16x8*)(Ksc + col * 64 + ((g0r ^ (col & 7)) * 8));
        sB[n] = __builtin_amdgcn_mfma_f32_16x16x32_bf16(aqk, bk, sB[n], 0, 0, 0);
      }
    }
    if (doA) {
#pragma unroll
      for (int kk = 0; kk < 2; ++kk) {
        const int g0r = kk * 4 + hi;
        const bf16x8 aqk = kk ? aqA1 : aqA0;
#pragma unroll
        for (int n = 0; n < 4; ++n) {
          const int col = n * 16 + cc;
          bf16x8 bk = *(const bf16x8*)(Ksc + col * 64 + ((g0r ^ (col & 7)) * 8));
          sA[n] = __builtin_amdgcn_mfma_f32_16x16x32_bf16(aqk, bk, sA[n], 0, 0, 0);
        }
      }
    }
    __builtin_amdgcn_s_setprio(0);
    sm_pv(sB, oaccB, rsB, baseB4, PwB, qwB, t == nB - 1, kv0, Vsc);
    if (doA) sm_pv(sA, oaccA, rsA, baseA4, PwA, qwA, t == nA - 1, kv0, Vsc);
    if (havenext) {
      const int nxt = cur ^ 1;
      *(int4v*)(&Ks[nxt][s0]) = kr0;
      *(int4v*)(&Ks[nxt][s1]) = kr1;
      *(int4v*)(&Vs[nxt][s0]) = vr0;
      *(int4v*)(&Vs[nxt][s1]) = vr1;
    }
    __syncthreads();
    cur ^= 1;
  }
  {
    const int rr = hi * 4;
#pragma unroll
    for (int n = 0; n < 4; ++n)
#pragma unroll
      for (int j = 0; j < 4; ++j) {
        const int row = qwA + rr + j;
        o[(size_t)(b * 2048 + row) * 1024 + h * 64 + n * 16 + cc] = f2b(oaccA[n][j] / rsA[j]);
      }
#pragma unroll
    for (int n = 0; n < 4; ++n)
#pragma unroll
      for (int j = 0; j < 4; ++j) {
        const int row = qwB + rr + j;
        o[(size_t)(b * 2048 + row) * 1024 + h * 64 + n * 16 + cc] = f2b(oaccB[n][j] / rsB[j]);
      }
  }
}

extern "C" void kernel_launch(void* const* d_in, const int* in_sizes, int n_in,
                              void* d_out, int out_size, void* d_ws, size_t ws_size,
                              hipStream_t stream) {
  (void)in_sizes; (void)n_in; (void)out_size; (void)ws_size;
  const float* x      = (const float*)d_in[0];
  const float* Wq     = (const float*)d_in[1];
  const float* Wk     = (const float*)d_in[2];
  const float* Wv     = (const float*)d_in[3];
  const float* Wo     = (const float*)d_in[4];
  const float* scale1 = (const float*)d_in[5];
  const float* scale2 = (const float*)d_in[6];
  const float* W1     = (const float*)d_in[7];
  const float* b1     = (const float*)d_in[8];
  const float* Wg     = (const float*)d_in[9];
  const float* bg     = (const float*)d_in[10];
  const float* Wl     = (const float*)d_in[11];
  const float* bl     = (const float*)d_in[12];
  const float* beta   = (const float*)d_in[13];
  float* out = (float*)d_out;

  char* ws = (char*)d_ws;
  float* sums         = (float*)ws;                                    // 256 B
  unsigned short* WT  = (unsigned short*)(ws + 16384);                 // 7M bf16 (14 MB)
  unsigned short* h   = (unsigned short*)(ws + 16384 + 14680064);      // 4M bf16 (8 MB)
  unsigned short* qkv = (unsigned short*)((char*)h + 8388608);         // 12M bf16 (24 MB)
  unsigned short* vt  = (unsigned short*)((char*)qkv + 25165824);      // 4M bf16 (8 MB)
  float* x1           = (float*)((char*)vt + 8388608);                 // 4M fp32 (16 MB)
  unsigned short* ob  = h;                   // reuse (h dead after qkv GEMM)
  unsigned short* t1  = qkv;                 // reuse (qkv dead after attention)

  hipMemsetAsync(sums, 0, 256, stream);

  // --- attention sublayer ---
  k_transpose_w7<<<dim3(32, 32, 7), 256, 0, stream>>>(Wq, Wk, Wv, Wo, W1, Wg, Wl, WT);
  k_reduce_sq<<<dim3(256, 2), 256, 0, stream>>>(x, sums);
  k_rmsnorm<<<4096, 256, 0, stream>>>(x, scale1, sums, h);
  k_gemm<5, 4><<<dim3(24, 32), 256, 0, stream>>>(h, WT, (void*)qkv, nullptr, nullptr, nullptr, nullptr, 3072, nullptr);
  k_transpose_v<<<dim3(2, 64, 32), 256, 0, stream>>>(qkv, vt);
  k_attn<<<512, 256, 0, stream>>>(qkv, vt, ob);
  k_gemm<1, 2><<<dim3(16, 32), 256, 0, stream>>>(ob, WT + 3145728, (void*)x1, x, nullptr, nullptr, nullptr, 1024, sums + 2);

  // --- FFN sublayer (sums[2..3] filled by fused GEMM epilogue) ---
  k_rmsnorm<<<4096, 256, 0, stream>>>(x1, scale2, sums + 2, h);
  k_gemm<2, 2><<<dim3(16, 32), 256, 0, stream>>>(h, WT + 4194304, (void*)t1, b1, nullptr, nullptr, nullptr, 1024, nullptr);
  k_gemm<4, 4><<<dim3(16, 32), 256, 0, stream>>>(t1, WT + 5242880, (void*)out, bg, bl, x1, beta, 1024, nullptr);
}

// Round 13
// 344.116 us; speedup vs baseline: 1.2370x; 1.0205x over previous
//
#include <hip/hip_runtime.h>
#include <hip/hip_bf16.h>

typedef __attribute__((ext_vector_type(8))) short bf16x8;
typedef __attribute__((ext_vector_type(4))) float f32x4;
typedef __attribute__((ext_vector_type(4))) int int4v;

#define DEV static __device__ __forceinline__

DEV float b2f(unsigned short u) { union { unsigned int i; float f; } c; c.i = ((unsigned int)u) << 16; return c.f; }
DEV unsigned short f2b(float f) {
  __hip_bfloat16 h = __float2bfloat16(f);
  unsigned short u; __builtin_memcpy(&u, &h, 2); return u;
}

DEV void gload16(const void* g, void* l) {
  __builtin_amdgcn_global_load_lds(
      (const __attribute__((address_space(1))) unsigned int*)(g),
      (__attribute__((address_space(3))) unsigned int*)(l), 16, 0, 0);
}

// ---------------- all 7 weight transposes in one launch ----------------
__global__ __launch_bounds__(256) void k_transpose_w7(const float* __restrict__ Wq,
                                                      const float* __restrict__ Wk,
                                                      const float* __restrict__ Wv,
                                                      const float* __restrict__ Wo,
                                                      const float* __restrict__ W1,
                                                      const float* __restrict__ Wg,
                                                      const float* __restrict__ Wl,
                                                      unsigned short* __restrict__ WT) {
  __shared__ float tile[32][33];
  const float* W;
  switch (blockIdx.z) {
    case 0: W = Wq; break; case 1: W = Wk; break; case 2: W = Wv; break;
    case 3: W = Wo; break; case 4: W = W1; break; case 5: W = Wg; break;
    default: W = Wl; break;
  }
  unsigned short* dst = WT + (size_t)blockIdx.z * 1048576;
  const int tx = threadIdx.x & 31, ty = threadIdx.x >> 5;
  const int c0 = blockIdx.x * 32, r0 = blockIdx.y * 32;
#pragma unroll
  for (int i = 0; i < 4; ++i)
    tile[ty + i * 8][tx] = W[(size_t)(r0 + ty + i * 8) * 1024 + c0 + tx];
  __syncthreads();
#pragma unroll
  for (int i = 0; i < 4; ++i)
    dst[(size_t)(c0 + ty + i * 8) * 1024 + r0 + tx] = f2b(tile[tx][ty + i * 8]);
}

// ---------------- per-batch sum of squares ----------------
__global__ __launch_bounds__(256) void k_reduce_sq(const float* __restrict__ x,
                                                   float* __restrict__ sums) {
  const int b = blockIdx.y;
  const float4* xb = (const float4*)(x + (size_t)b * 2097152);
  float s = 0.f;
  for (int i = blockIdx.x * 256 + threadIdx.x; i < 524288; i += 256 * gridDim.x) {
    float4 v = xb[i];
    s += v.x * v.x + v.y * v.y + v.z * v.z + v.w * v.w;
  }
  __shared__ float red[256];
  red[threadIdx.x] = s;
  __syncthreads();
  for (int st = 128; st > 0; st >>= 1) {
    if (threadIdx.x < st) red[threadIdx.x] += red[threadIdx.x + st];
    __syncthreads();
  }
  if (threadIdx.x == 0) atomicAdd(&sums[b], red[0]);
}

// ---------------- rmsnorm ----------------
__global__ __launch_bounds__(256) void k_rmsnorm(const float* __restrict__ x,
                                                 const float* __restrict__ scale,
                                                 const float* __restrict__ sums,
                                                 unsigned short* __restrict__ out) {
  const int idx = blockIdx.x * 256 + threadIdx.x;
  const int e = idx * 4;
  const int m = e >> 10, d = e & 1023;
  const int b = m >> 11, s = m & 2047;
  const float inv = rsqrtf(sums[b] * (1.0f / 2097152.0f));
  float4 xv = *(const float4*)(x + (size_t)e);
  float4 sv = *(const float4*)(scale + (size_t)s * 1024 + d);
  ushort4 o;
  o.x = f2b(xv.x * sv.x * inv); o.y = f2b(xv.y * sv.y * inv);
  o.z = f2b(xv.z * sv.z * inv); o.w = f2b(xv.w * sv.w * inv);
  *(ushort4*)(out + e) = o;
}

// ---------------- GEMM: C[4096,N] = A[4096,1024] @ Bt[N,1024]^T ----------------
// v2: minimum 2-phase pipeline (T3-lite): double-buffered LDS, next-tile
// global_load_lds issued BEFORE current-tile compute, ONE barrier per iter.
// EPI 1: fp32 (aux[row,col]+acc) + fused batch sumsq. EPI 2: bf16 (acc+aux[col]).
// EPI 4: fused SwiGLU. EPI 5: bf16 store with fused RoPE for cols<2048.
template <int EPI, int NREP>
__global__ __launch_bounds__(256) void k_gemm(const unsigned short* __restrict__ A,
                                              const unsigned short* __restrict__ Bt,
                                              void* __restrict__ Cout,
                                              const float* __restrict__ aux,
                                              const float* __restrict__ aux2,
                                              const float* __restrict__ x1p,
                                              const float* __restrict__ betap,
                                              const int N,
                                              float* __restrict__ ss) {
  constexpr int BN = NREP * 32;
  __shared__ short As[2][128 * 64];
  __shared__ short Bs[2][BN * 64];
  const int tid = threadIdx.x;
  const int w = tid >> 6, l = tid & 63;
  const int brow = blockIdx.y * 128;
  const int bcol = blockIdx.x * (EPI == 4 ? 64 : BN);
  const int wr = (w >> 1) * 64;
  const int wc = (EPI == 4) ? (w & 1) * 32 : (w & 1) * (NREP * 16);
  const int lr = l >> 3, lg = l & 7;
  f32x4 acc[4][NREP] = {};
  const short* Ag = (const short*)A;
  const short* Bg = (const short*)Bt;

  auto STAGE = [&](int buf, int k0) {
#pragma unroll
    for (int p = 0; p < 4; ++p) {
      const int row = p * 32 + w * 8 + lr;
      gload16(Ag + (size_t)(brow + row) * 1024 + k0 + lg * 8,
              (char*)&As[buf][0] + (size_t)(p * 32 + w * 8) * 128);
    }
#pragma unroll
    for (int p = 0; p < NREP; ++p) {
      const int row = p * 32 + w * 8 + lr;
      size_t goff;
      if (EPI == 4 && p >= 2)
        goff = (size_t)1048576 + (size_t)(bcol + row - 64) * 1024;  // Wl section
      else
        goff = (size_t)(bcol + row) * 1024;
      gload16(Bg + goff + k0 + lg * 8,
              (char*)&Bs[buf][0] + (size_t)(p * 32 + w * 8) * 128);
    }
  };

  STAGE(0, 0);
  __syncthreads();  // drains vmcnt -> tile 0 visible
  int cur = 0;
  for (int t = 0; t < 16; ++t) {
    if (t < 15) STAGE(cur ^ 1, (t + 1) * 64);  // prefetch next tile (other buffer)
#pragma unroll
    for (int kk = 0; kk < 2; ++kk) {
      const int g0 = kk * 4 + (l >> 4);
      bf16x8 af[4], bfr[NREP];
#pragma unroll
      for (int m = 0; m < 4; ++m)
        af[m] = *(const bf16x8*)(&As[cur][0] + (wr + m * 16 + (l & 15)) * 64 + g0 * 8);
#pragma unroll
      for (int n = 0; n < NREP; ++n) {
        int bsrow;
        if (EPI == 4) bsrow = (n < 2) ? (wc + n * 16 + (l & 15)) : (64 + wc + (n - 2) * 16 + (l & 15));
        else bsrow = wc + n * 16 + (l & 15);
        bfr[n] = *(const bf16x8*)(&Bs[cur][0] + bsrow * 64 + g0 * 8);
      }
      __builtin_amdgcn_s_setprio(1);
#pragma unroll
      for (int m = 0; m < 4; ++m)
#pragma unroll
        for (int n = 0; n < NREP; ++n)
          acc[m][n] = __builtin_amdgcn_mfma_f32_16x16x32_bf16(af[m], bfr[n], acc[m][n], 0, 0, 0);
      __builtin_amdgcn_s_setprio(0);
    }
    __syncthreads();  // drains prefetch vmcnt + protects cur from next overwrite
    cur ^= 1;
  }
  const int rr = (l >> 4) * 4, cc = l & 15;
  if (EPI == 5) {
    const bool dorope = (bcol < 2048);   // block-uniform (128-col tiles align to 2048)
    if (dorope) {
      float th[NREP];
#pragma unroll
      for (int n = 0; n < NREP; ++n)
        th[n] = exp2f(-((float)(((bcol + wc + n * 16 + cc) & 1023) >> 1) - 1.0f) * 0.0259525627f);
#pragma unroll
      for (int m = 0; m < 4; ++m)
#pragma unroll
        for (int n = 0; n < NREP; ++n) {
          const int col = bcol + wc + n * 16 + cc;
#pragma unroll
          for (int j = 0; j < 4; ++j) {
            const int row = brow + wr + m * 16 + rr + j;
            const float vo = acc[m][n][j];
            const float vp = __shfl_xor(vo, 1);  // partner column (col^1)
            float sn, cs;
            __sincosf((float)(row & 2047) * th[n], &sn, &cs);
            const float r = (cc & 1) ? (cs * vo - sn * vp) : (cs * vo + sn * vp);
            ((unsigned short*)Cout)[(size_t)row * N + col] = f2b(r);
          }
        }
    } else {
#pragma unroll
      for (int m = 0; m < 4; ++m)
#pragma unroll
        for (int n = 0; n < NREP; ++n) {
          const int col = bcol + wc + n * 16 + cc;
#pragma unroll
          for (int j = 0; j < 4; ++j) {
            const int row = brow + wr + m * 16 + rr + j;
            ((unsigned short*)Cout)[(size_t)row * N + col] = f2b(acc[m][n][j]);
          }
        }
    }
    return;
  }
  if (EPI == 4) {
    const float bt = betap[0];
#pragma unroll
    for (int m = 0; m < 4; ++m)
#pragma unroll
      for (int nn = 0; nn < 2; ++nn) {
        const int col = bcol + wc + nn * 16 + cc;
#pragma unroll
        for (int j = 0; j < 4; ++j) {
          const int row = brow + wr + m * 16 + rr + j;
          const float gv = acc[m][nn][j] + aux[col];
          const float lv = acc[m][nn + 2][j] + aux2[col];
          const float sw = gv / (1.f + __expf(-bt * gv));
          ((float*)Cout)[(size_t)row * 1024 + col] = x1p[(size_t)row * 1024 + col] + sw * lv;
        }
      }
    return;
  }
  float sq = 0.f;
#pragma unroll
  for (int m = 0; m < 4; ++m)
#pragma unroll
    for (int n = 0; n < NREP; ++n) {
      const int col = bcol + wc + n * 16 + cc;
#pragma unroll
      for (int j = 0; j < 4; ++j) {
        const int row = brow + wr + m * 16 + rr + j;
        float v = acc[m][n][j];
        if (EPI == 1) {
          const float v2 = aux[(size_t)row * N + col] + v;
          ((float*)Cout)[(size_t)row * N + col] = v2;
          sq += v2 * v2;
        } else {
          ((unsigned short*)Cout)[(size_t)row * N + col] = f2b(v + aux[col]);
        }
      }
    }
  if (EPI == 1) {
#pragma unroll
    for (int off = 1; off < 64; off <<= 1) sq += __shfl_xor(sq, off);
    if (l == 0) atomicAdd(&ss[brow >> 11], sq);
  }
}

// ---------------- V transpose + fused RoPE on V ----------------
__global__ __launch_bounds__(256) void k_transpose_v(const unsigned short* __restrict__ qkv,
                                                     unsigned short* __restrict__ vt) {
  __shared__ unsigned short tile[32][33];
  const int tx = threadIdx.x & 31, ty = threadIdx.x >> 5;
  const int bh = blockIdx.z;
  const int b = bh >> 4, h = bh & 15;
  const int d0 = blockIdx.x * 32, s0 = blockIdx.y * 32;
#pragma unroll
  for (int i = 0; i < 4; ++i)
    tile[ty + i * 8][tx] = qkv[(size_t)(b * 2048 + s0 + ty + i * 8) * 3072 + 2048 + h * 64 + d0 + tx];
  __syncthreads();
  const float sv = (float)(s0 + tx);
  const int par = ty & 1;
#pragma unroll
  for (int i = 0; i < 4; ++i) {
    const int dsec = h * 64 + d0 + ty + i * 8;   // d within the 1024-wide V section
    const float th = exp2f(-((float)(dsec >> 1) - 1.0f) * 0.0259525627f);
    float sn, cs;
    __sincosf(sv * th, &sn, &cs);
    const float vo = b2f(tile[tx][ty + i * 8]);
    const float vp = b2f(tile[tx][(ty ^ 1) + i * 8]);  // partner d^1, same s
    const float r = par ? (cs * vo - sn * vp) : (cs * vo + sn * vp);
    vt[((size_t)bh * 64 + d0 + ty + i * 8) * 2048 + s0 + tx] = f2b(r);
  }
}

// ---------------- flash attention v5: interleaved q-tile pair, NO-MAX softmax ----------------
__global__ __launch_bounds__(256) void k_attn(const unsigned short* __restrict__ qkv,
                                              const unsigned short* __restrict__ vt,
                                              unsigned short* __restrict__ o) {
  __shared__ short Ks[2][4096];
  __shared__ short Vs[2][4096];
  __shared__ short Ps[8][1280];
  const int id = blockIdx.x;
  const int xcd = id & 7, q = id >> 3;
  const int p = q & 15, g = (q >> 4) * 8 + xcd;
  const int h = g & 15, b = g >> 4;
  const int qtA = p, qtB = 31 - p;
  const int nA = qtA + 1, nB = qtB + 1;  // nA <= 16 <= nB
  const int tid = threadIdx.x, w = tid >> 6, l = tid & 63;
  const int cc = l & 15, hi = l >> 4;
  const int qwA = qtA * 64 + w * 16, qwB = qtB * 64 + w * 16;
  const short* qg = (const short*)qkv;
  bf16x8 aqA0, aqA1, aqB0, aqB1;
  {
    const short* baseA = qg + (size_t)(b * 2048 + qwA + cc) * 3072 + h * 64 + hi * 8;
    aqA0 = *(const bf16x8*)baseA;
    aqA1 = *(const bf16x8*)(baseA + 32);
    const short* baseB = qg + (size_t)(b * 2048 + qwB + cc) * 3072 + h * 64 + hi * 8;
    aqB0 = *(const bf16x8*)baseB;
    aqB1 = *(const bf16x8*)(baseB + 32);
  }
  const float slope2 = exp2f(-0.5f * (float)(h + 1)) * 1.44269504f;  // log2 domain
  const float C1 = 0.125f * 1.44269504f;
  const float step = slope2 * 64.f;
  bf16x8 onesf;
#pragma unroll
  for (int z = 0; z < 8; ++z) onesf[z] = (short)0x3F80;  // bf16 1.0
  f32x4 oaccA[4] = {}, oaccB[4] = {};
  f32x4 rsA = {}, rsB = {};
  float baseA4[4], baseB4[4];
#pragma unroll
  for (int n = 0; n < 4; ++n) {
    baseA4[n] = slope2 * (float)(n * 16 + cc - qwA - hi * 4);
    baseB4[n] = slope2 * (float)(n * 16 + cc - qwB - hi * 4);
  }
  short* PwA = &Ps[w][0];
  short* PwB = &Ps[w + 4][0];
  const int c0 = tid, c1 = tid + 256;
  const int r0 = c0 >> 3, g0c = c0 & 7;
  const int r1 = c1 >> 3, g1c = c1 & 7;
  const int s0 = r0 * 64 + ((g0c ^ (r0 & 7)) * 8);
  const int s1 = r1 * 64 + ((g1c ^ (r1 & 7)) * 8);
  const short* kbase = qg + (size_t)(b * 2048) * 3072 + 1024 + h * 64;
  const short* vbase = (const short*)vt + (size_t)(b * 16 + h) * 64 * 2048;
  // prologue: stage tile 0
  *(int4v*)(&Ks[0][s0]) = *(const int4v*)(kbase + (size_t)r0 * 3072 + g0c * 8);
  *(int4v*)(&Ks[0][s1]) = *(const int4v*)(kbase + (size_t)r1 * 3072 + g1c * 8);
  *(int4v*)(&Vs[0][s0]) = *(const int4v*)(vbase + (size_t)r0 * 2048 + g0c * 8);
  *(int4v*)(&Vs[0][s1]) = *(const int4v*)(vbase + (size_t)r1 * 2048 + g1c * 8);
  __syncthreads();

  auto sm_pv = [&](f32x4 (&sacc)[4], f32x4 (&oacc)[4], f32x4& rs, float (&base)[4],
                   short* Pw, const int qw, const bool domask, const int kv0,
                   const short* Vsc) {
#pragma unroll
    for (int n = 0; n < 4; ++n) {
#pragma unroll
      for (int j = 0; j < 4; ++j) {
        float v = fmaf(sacc[n][j], C1, base[n] - slope2 * (float)j);
        if (domask) {
          const int kvg = kv0 + n * 16 + cc;
          const int qrow = qw + hi * 4 + j;
          if (kvg > qrow) v = -1e30f;   // exp2 -> 0
        }
        Pw[(hi * 4 + j) * 80 + n * 16 + cc] = (short)f2b(exp2f(v));
      }
      base[n] += step;
    }
    __builtin_amdgcn_s_setprio(1);
#pragma unroll
    for (int kk2 = 0; kk2 < 2; ++kk2) {
      bf16x8 pf = *(const bf16x8*)(Pw + cc * 80 + kk2 * 32 + hi * 8);
      rs = __builtin_amdgcn_mfma_f32_16x16x32_bf16(pf, onesf, rs, 0, 0, 0);
#pragma unroll
      for (int n = 0; n < 4; ++n) {
        const int dr = n * 16 + cc;
        bf16x8 vf = *(const bf16x8*)(Vsc + dr * 64 + (((kk2 * 4 + hi) ^ (dr & 7)) * 8));
        oacc[n] = __builtin_amdgcn_mfma_f32_16x16x32_bf16(pf, vf, oacc[n], 0, 0, 0);
      }
    }
    __builtin_amdgcn_s_setprio(0);
  };

  int cur = 0;
  for (int t = 0; t < nB; ++t) {
    int4v kr0, kr1, vr0, vr1;
    const bool havenext = (t + 1 < nB);
    if (havenext) {
      const size_t k0n = (size_t)(t + 1) * 64;
      kr0 = *(const int4v*)(kbase + (k0n + r0) * 3072 + g0c * 8);
      kr1 = *(const int4v*)(kbase + (k0n + r1) * 3072 + g1c * 8);
      vr0 = *(const int4v*)(vbase + (size_t)r0 * 2048 + k0n + g0c * 8);
      vr1 = *(const int4v*)(vbase + (size_t)r1 * 2048 + k0n + g1c * 8);
    }
    const int kv0 = t * 64;
    const short* Ksc = &Ks[cur][0];
    const short* Vsc = &Vs[cur][0];
    const bool doA = (t < nA);
    f32x4 sB[4] = {}, sA[4] = {};
    __builtin_amdgcn_s_setprio(1);
#pragma unroll
    for (int kk = 0; kk < 2; ++kk) {
      const int g0r = kk * 4 + hi;
      const bf16x8 aqk = kk ? aqB1 : aqB0;
#pragma unroll
      for (int n = 0; n < 4; ++n) {
        const int col = n * 16 + cc;
        bf16x8 bk = *(const bf16x8*)(Ksc + col * 64 + ((g0r ^ (col & 7)) * 8));
        sB[n] = __builtin_amdgcn_mfma_f32_16x16x32_bf16(aqk, bk, sB[n], 0, 0, 0);
      }
    }
    if (doA) {
#pragma unroll
      for (int kk = 0; kk < 2; ++kk) {
        const int g0r = kk * 4 + hi;
        const bf16x8 aqk = kk ? aqA1 : aqA0;
#pragma unroll
        for (int n = 0; n < 4; ++n) {
          const int col = n * 16 + cc;
          bf16x8 bk = *(const bf16x8*)(Ksc + col * 64 + ((g0r ^ (col & 7)) * 8));
          sA[n] = __builtin_amdgcn_mfma_f32_16x16x32_bf16(aqk, bk, sA[n], 0, 0, 0);
        }
      }
    }
    __builtin_amdgcn_s_setprio(0);
    sm_pv(sB, oaccB, rsB, baseB4, PwB, qwB, t == nB - 1, kv0, Vsc);
    if (doA) sm_pv(sA, oaccA, rsA, baseA4, PwA, qwA, t == nA - 1, kv0, Vsc);
    if (havenext) {
      const int nxt = cur ^ 1;
      *(int4v*)(&Ks[nxt][s0]) = kr0;
      *(int4v*)(&Ks[nxt][s1]) = kr1;
      *(int4v*)(&Vs[nxt][s0]) = vr0;
      *(int4v*)(&Vs[nxt][s1]) = vr1;
    }
    __syncthreads();
    cur ^= 1;
  }
  {
    const int rr = hi * 4;
#pragma unroll
    for (int n = 0; n < 4; ++n)
#pragma unroll
      for (int j = 0; j < 4; ++j) {
        const int row = qwA + rr + j;
        o[(size_t)(b * 2048 + row) * 1024 + h * 64 + n * 16 + cc] = f2b(oaccA[n][j] / rsA[j]);
      }
#pragma unroll
    for (int n = 0; n < 4; ++n)
#pragma unroll
      for (int j = 0; j < 4; ++j) {
        const int row = qwB + rr + j;
        o[(size_t)(b * 2048 + row) * 1024 + h * 64 + n * 16 + cc] = f2b(oaccB[n][j] / rsB[j]);
      }
  }
}

extern "C" void kernel_launch(void* const* d_in, const int* in_sizes, int n_in,
                              void* d_out, int out_size, void* d_ws, size_t ws_size,
                              hipStream_t stream) {
  (void)in_sizes; (void)n_in; (void)out_size; (void)ws_size;
  const float* x      = (const float*)d_in[0];
  const float* Wq     = (const float*)d_in[1];
  const float* Wk     = (const float*)d_in[2];
  const float* Wv     = (const float*)d_in[3];
  const float* Wo     = (const float*)d_in[4];
  const float* scale1 = (const float*)d_in[5];
  const float* scale2 = (const float*)d_in[6];
  const float* W1     = (const float*)d_in[7];
  const float* b1     = (const float*)d_in[8];
  const float* Wg     = (const float*)d_in[9];
  const float* bg     = (const float*)d_in[10];
  const float* Wl     = (const float*)d_in[11];
  const float* bl     = (const float*)d_in[12];
  const float* beta   = (const float*)d_in[13];
  float* out = (float*)d_out;

  char* ws = (char*)d_ws;
  float* sums         = (float*)ws;                                    // 256 B
  unsigned short* WT  = (unsigned short*)(ws + 16384);                 // 7M bf16 (14 MB)
  unsigned short* h   = (unsigned short*)(ws + 16384 + 14680064);      // 4M bf16 (8 MB)
  unsigned short* qkv = (unsigned short*)((char*)h + 8388608);         // 12M bf16 (24 MB)
  unsigned short* vt  = (unsigned short*)((char*)qkv + 25165824);      // 4M bf16 (8 MB)
  float* x1           = (float*)((char*)vt + 8388608);                 // 4M fp32 (16 MB)
  unsigned short* ob  = h;                   // reuse (h dead after qkv GEMM)
  unsigned short* t1  = qkv;                 // reuse (qkv dead after attention)

  hipMemsetAsync(sums, 0, 256, stream);

  // --- attention sublayer ---
  k_transpose_w7<<<dim3(32, 32, 7), 256, 0, stream>>>(Wq, Wk, Wv, Wo, W1, Wg, Wl, WT);
  k_reduce_sq<<<dim3(256, 2), 256, 0, stream>>>(x, sums);
  k_rmsnorm<<<4096, 256, 0, stream>>>(x, scale1, sums, h);
  k_gemm<5, 4><<<dim3(24, 32), 256, 0, stream>>>(h, WT, (void*)qkv, nullptr, nullptr, nullptr, nullptr, 3072, nullptr);
  k_transpose_v<<<dim3(2, 64, 32), 256, 0, stream>>>(qkv, vt);
  k_attn<<<512, 256, 0, stream>>>(qkv, vt, ob);
  k_gemm<1, 2><<<dim3(16, 32), 256, 0, stream>>>(ob, WT + 3145728, (void*)x1, x, nullptr, nullptr, nullptr, 1024, sums + 2);

  // --- FFN sublayer (sums[2..3] filled by fused GEMM epilogue) ---
  k_rmsnorm<<<4096, 256, 0, stream>>>(x1, scale2, sums + 2, h);
  k_gemm<2, 2><<<dim3(16, 32), 256, 0, stream>>>(h, WT + 4194304, (void*)t1, b1, nullptr, nullptr, nullptr, 1024, nullptr);
  k_gemm<4, 4><<<dim3(16, 32), 256, 0, stream>>>(t1, WT + 5242880, (void*)out, bg, bl, x1, beta, 1024, nullptr);
}

// Round 14
// 342.199 us; speedup vs baseline: 1.2440x; 1.0056x over previous
//
#include <hip/hip_runtime.h>
#include <hip/hip_bf16.h>

typedef __attribute__((ext_vector_type(8))) short bf16x8;
typedef __attribute__((ext_vector_type(4))) float f32x4;
typedef __attribute__((ext_vector_type(4))) int int4v;

#define DEV static __device__ __forceinline__

DEV float b2f(unsigned short u) { union { unsigned int i; float f; } c; c.i = ((unsigned int)u) << 16; return c.f; }
DEV unsigned short f2b(float f) {
  __hip_bfloat16 h = __float2bfloat16(f);
  unsigned short u; __builtin_memcpy(&u, &h, 2); return u;
}

DEV void gload16(const void* g, void* l) {
  __builtin_amdgcn_global_load_lds(
      (const __attribute__((address_space(1))) unsigned int*)(g),
      (__attribute__((address_space(3))) unsigned int*)(l), 16, 0, 0);
}

// ---------------- all 7 weight transposes in one launch ----------------
__global__ __launch_bounds__(256) void k_transpose_w7(const float* __restrict__ Wq,
                                                      const float* __restrict__ Wk,
                                                      const float* __restrict__ Wv,
                                                      const float* __restrict__ Wo,
                                                      const float* __restrict__ W1,
                                                      const float* __restrict__ Wg,
                                                      const float* __restrict__ Wl,
                                                      unsigned short* __restrict__ WT) {
  __shared__ float tile[32][33];
  const float* W;
  switch (blockIdx.z) {
    case 0: W = Wq; break; case 1: W = Wk; break; case 2: W = Wv; break;
    case 3: W = Wo; break; case 4: W = W1; break; case 5: W = Wg; break;
    default: W = Wl; break;
  }
  unsigned short* dst = WT + (size_t)blockIdx.z * 1048576;
  const int tx = threadIdx.x & 31, ty = threadIdx.x >> 5;
  const int c0 = blockIdx.x * 32, r0 = blockIdx.y * 32;
#pragma unroll
  for (int i = 0; i < 4; ++i)
    tile[ty + i * 8][tx] = W[(size_t)(r0 + ty + i * 8) * 1024 + c0 + tx];
  __syncthreads();
#pragma unroll
  for (int i = 0; i < 4; ++i)
    dst[(size_t)(c0 + ty + i * 8) * 1024 + r0 + tx] = f2b(tile[tx][ty + i * 8]);
}

// ---------------- per-batch sum of squares ----------------
__global__ __launch_bounds__(256) void k_reduce_sq(const float* __restrict__ x,
                                                   float* __restrict__ sums) {
  const int b = blockIdx.y;
  const float4* xb = (const float4*)(x + (size_t)b * 2097152);
  float s = 0.f;
  for (int i = blockIdx.x * 256 + threadIdx.x; i < 524288; i += 256 * gridDim.x) {
    float4 v = xb[i];
    s += v.x * v.x + v.y * v.y + v.z * v.z + v.w * v.w;
  }
  __shared__ float red[256];
  red[threadIdx.x] = s;
  __syncthreads();
  for (int st = 128; st > 0; st >>= 1) {
    if (threadIdx.x < st) red[threadIdx.x] += red[threadIdx.x + st];
    __syncthreads();
  }
  if (threadIdx.x == 0) atomicAdd(&sums[b], red[0]);
}

// ---------------- rmsnorm ----------------
__global__ __launch_bounds__(256) void k_rmsnorm(const float* __restrict__ x,
                                                 const float* __restrict__ scale,
                                                 const float* __restrict__ sums,
                                                 unsigned short* __restrict__ out) {
  const int idx = blockIdx.x * 256 + threadIdx.x;
  const int e = idx * 4;
  const int m = e >> 10, d = e & 1023;
  const int b = m >> 11, s = m & 2047;
  const float inv = rsqrtf(sums[b] * (1.0f / 2097152.0f));
  float4 xv = *(const float4*)(x + (size_t)e);
  float4 sv = *(const float4*)(scale + (size_t)s * 1024 + d);
  ushort4 o;
  o.x = f2b(xv.x * sv.x * inv); o.y = f2b(xv.y * sv.y * inv);
  o.z = f2b(xv.z * sv.z * inv); o.w = f2b(xv.w * sv.w * inv);
  *(ushort4*)(out + e) = o;
}

// ---------------- GEMM: C[4096,N] = A[4096,1024] @ Bt[N,1024]^T ----------------
// 2-phase pipeline: double-buffered LDS, next-tile global_load_lds issued
// BEFORE current-tile compute, one barrier per iter.
// EPI 1: fp32 (aux[row,col]+acc) + fused batch sumsq. EPI 2: bf16 (acc+aux[col]).
// EPI 4: fused SwiGLU. EPI 5: bf16 store with fused RoPE for cols<2048.
template <int EPI, int NREP>
__global__ __launch_bounds__(256) void k_gemm(const unsigned short* __restrict__ A,
                                              const unsigned short* __restrict__ Bt,
                                              void* __restrict__ Cout,
                                              const float* __restrict__ aux,
                                              const float* __restrict__ aux2,
                                              const float* __restrict__ x1p,
                                              const float* __restrict__ betap,
                                              const int N,
                                              float* __restrict__ ss) {
  constexpr int BN = NREP * 32;
  __shared__ short As[2][128 * 64];
  __shared__ short Bs[2][BN * 64];
  const int tid = threadIdx.x;
  const int w = tid >> 6, l = tid & 63;
  const int brow = blockIdx.y * 128;
  const int bcol = blockIdx.x * (EPI == 4 ? 64 : BN);
  const int wr = (w >> 1) * 64;
  const int wc = (EPI == 4) ? (w & 1) * 32 : (w & 1) * (NREP * 16);
  const int lr = l >> 3, lg = l & 7;
  f32x4 acc[4][NREP] = {};
  const short* Ag = (const short*)A;
  const short* Bg = (const short*)Bt;

  auto STAGE = [&](int buf, int k0) {
#pragma unroll
    for (int p = 0; p < 4; ++p) {
      const int row = p * 32 + w * 8 + lr;
      gload16(Ag + (size_t)(brow + row) * 1024 + k0 + lg * 8,
              (char*)&As[buf][0] + (size_t)(p * 32 + w * 8) * 128);
    }
#pragma unroll
    for (int p = 0; p < NREP; ++p) {
      const int row = p * 32 + w * 8 + lr;
      size_t goff;
      if (EPI == 4 && p >= 2)
        goff = (size_t)1048576 + (size_t)(bcol + row - 64) * 1024;  // Wl section
      else
        goff = (size_t)(bcol + row) * 1024;
      gload16(Bg + goff + k0 + lg * 8,
              (char*)&Bs[buf][0] + (size_t)(p * 32 + w * 8) * 128);
    }
  };

  STAGE(0, 0);
  __syncthreads();  // drains vmcnt -> tile 0 visible
  int cur = 0;
  for (int t = 0; t < 16; ++t) {
    if (t < 15) STAGE(cur ^ 1, (t + 1) * 64);  // prefetch next tile (other buffer)
#pragma unroll
    for (int kk = 0; kk < 2; ++kk) {
      const int g0 = kk * 4 + (l >> 4);
      bf16x8 af[4], bfr[NREP];
#pragma unroll
      for (int m = 0; m < 4; ++m)
        af[m] = *(const bf16x8*)(&As[cur][0] + (wr + m * 16 + (l & 15)) * 64 + g0 * 8);
#pragma unroll
      for (int n = 0; n < NREP; ++n) {
        int bsrow;
        if (EPI == 4) bsrow = (n < 2) ? (wc + n * 16 + (l & 15)) : (64 + wc + (n - 2) * 16 + (l & 15));
        else bsrow = wc + n * 16 + (l & 15);
        bfr[n] = *(const bf16x8*)(&Bs[cur][0] + bsrow * 64 + g0 * 8);
      }
      __builtin_amdgcn_s_setprio(1);
#pragma unroll
      for (int m = 0; m < 4; ++m)
#pragma unroll
        for (int n = 0; n < NREP; ++n)
          acc[m][n] = __builtin_amdgcn_mfma_f32_16x16x32_bf16(af[m], bfr[n], acc[m][n], 0, 0, 0);
      __builtin_amdgcn_s_setprio(0);
    }
    __syncthreads();  // drains prefetch vmcnt + protects cur from next overwrite
    cur ^= 1;
  }
  const int rr = (l >> 4) * 4, cc = l & 15;
  if (EPI == 5) {
    const bool dorope = (bcol < 2048);   // block-uniform (128-col tiles align to 2048)
    if (dorope) {
      float th[NREP];
#pragma unroll
      for (int n = 0; n < NREP; ++n)
        th[n] = exp2f(-((float)(((bcol + wc + n * 16 + cc) & 1023) >> 1) - 1.0f) * 0.0259525627f);
#pragma unroll
      for (int m = 0; m < 4; ++m)
#pragma unroll
        for (int n = 0; n < NREP; ++n) {
          const int col = bcol + wc + n * 16 + cc;
#pragma unroll
          for (int j = 0; j < 4; ++j) {
            const int row = brow + wr + m * 16 + rr + j;
            const float vo = acc[m][n][j];
            const float vp = __shfl_xor(vo, 1);  // partner column (col^1)
            float sn, cs;
            __sincosf((float)(row & 2047) * th[n], &sn, &cs);
            const float r = (cc & 1) ? (cs * vo - sn * vp) : (cs * vo + sn * vp);
            ((unsigned short*)Cout)[(size_t)row * N + col] = f2b(r);
          }
        }
    } else {
#pragma unroll
      for (int m = 0; m < 4; ++m)
#pragma unroll
        for (int n = 0; n < NREP; ++n) {
          const int col = bcol + wc + n * 16 + cc;
#pragma unroll
          for (int j = 0; j < 4; ++j) {
            const int row = brow + wr + m * 16 + rr + j;
            ((unsigned short*)Cout)[(size_t)row * N + col] = f2b(acc[m][n][j]);
          }
        }
    }
    return;
  }
  if (EPI == 4) {
    const float bt = betap[0];
#pragma unroll
    for (int m = 0; m < 4; ++m)
#pragma unroll
      for (int nn = 0; nn < 2; ++nn) {
        const int col = bcol + wc + nn * 16 + cc;
#pragma unroll
        for (int j = 0; j < 4; ++j) {
          const int row = brow + wr + m * 16 + rr + j;
          const float gv = acc[m][nn][j] + aux[col];
          const float lv = acc[m][nn + 2][j] + aux2[col];
          const float sw = gv / (1.f + __expf(-bt * gv));
          ((float*)Cout)[(size_t)row * 1024 + col] = x1p[(size_t)row * 1024 + col] + sw * lv;
        }
      }
    return;
  }
  float sq = 0.f;
#pragma unroll
  for (int m = 0; m < 4; ++m)
#pragma unroll
    for (int n = 0; n < NREP; ++n) {
      const int col = bcol + wc + n * 16 + cc;
#pragma unroll
      for (int j = 0; j < 4; ++j) {
        const int row = brow + wr + m * 16 + rr + j;
        float v = acc[m][n][j];
        if (EPI == 1) {
          const float v2 = aux[(size_t)row * N + col] + v;
          ((float*)Cout)[(size_t)row * N + col] = v2;
          sq += v2 * v2;
        } else {
          ((unsigned short*)Cout)[(size_t)row * N + col] = f2b(v + aux[col]);
        }
      }
    }
  if (EPI == 1) {
#pragma unroll
    for (int off = 1; off < 64; off <<= 1) sq += __shfl_xor(sq, off);
    if (l == 0) atomicAdd(&ss[brow >> 11], sq);
  }
}

// ---------------- V transpose + fused RoPE on V ----------------
__global__ __launch_bounds__(256) void k_transpose_v(const unsigned short* __restrict__ qkv,
                                                     unsigned short* __restrict__ vt) {
  __shared__ unsigned short tile[32][33];
  const int tx = threadIdx.x & 31, ty = threadIdx.x >> 5;
  const int bh = blockIdx.z;
  const int b = bh >> 4, h = bh & 15;
  const int d0 = blockIdx.x * 32, s0 = blockIdx.y * 32;
#pragma unroll
  for (int i = 0; i < 4; ++i)
    tile[ty + i * 8][tx] = qkv[(size_t)(b * 2048 + s0 + ty + i * 8) * 3072 + 2048 + h * 64 + d0 + tx];
  __syncthreads();
  const float sv = (float)(s0 + tx);
  const int par = ty & 1;
#pragma unroll
  for (int i = 0; i < 4; ++i) {
    const int dsec = h * 64 + d0 + ty + i * 8;   // d within the 1024-wide V section
    const float th = exp2f(-((float)(dsec >> 1) - 1.0f) * 0.0259525627f);
    float sn, cs;
    __sincosf(sv * th, &sn, &cs);
    const float vo = b2f(tile[tx][ty + i * 8]);
    const float vp = b2f(tile[tx][(ty ^ 1) + i * 8]);  // partner d^1, same s
    const float r = par ? (cs * vo - sn * vp) : (cs * vo + sn * vp);
    vt[((size_t)bh * 64 + d0 + ty + i * 8) * 2048 + s0 + tx] = f2b(r);
  }
}

// ---------------- flash attention v6: single-chain, grid 1024, mixed-length dispatch ----------------
// One q-tile per block, 4 waves, 3 blocks/CU (42KB LDS). qt map ensures every
// consecutive-32 dispatch window contains all 32 tile lengths (CU balance).
// No-max softmax (round-12 validated): P = exp2(sc) unnormalized, divide at end.
__global__ __launch_bounds__(256) void k_attn(const unsigned short* __restrict__ qkv,
                                              const unsigned short* __restrict__ vt,
                                              unsigned short* __restrict__ o) {
  __shared__ short Ks[2][4096];
  __shared__ short Vs[2][4096];
  __shared__ short Ps[4][1280];
  const int id = blockIdx.x;
  const int g = id >> 5;
  const int qt = ((id & 31) + g) & 31;   // bijective per g; mixes lengths in dispatch order
  const int h = g & 15, b = g >> 4;
  const int nt = qt + 1;
  const int tid = threadIdx.x, w = tid >> 6, l = tid & 63;
  const int cc = l & 15, hi = l >> 4;
  const int qw = qt * 64 + w * 16;
  const short* qg = (const short*)qkv;
  bf16x8 aq0, aq1;
  {
    const short* base = qg + (size_t)(b * 2048 + qw + cc) * 3072 + h * 64 + hi * 8;
    aq0 = *(const bf16x8*)base;
    aq1 = *(const bf16x8*)(base + 32);
  }
  const float slope2 = exp2f(-0.5f * (float)(h + 1)) * 1.44269504f;  // log2 domain
  const float C1 = 0.125f * 1.44269504f;
  const float step = slope2 * 64.f;
  bf16x8 onesf;
#pragma unroll
  for (int z = 0; z < 8; ++z) onesf[z] = (short)0x3F80;  // bf16 1.0
  f32x4 oacc[4] = {};
  f32x4 rs = {};
  float base4[4];
#pragma unroll
  for (int n = 0; n < 4; ++n)
    base4[n] = slope2 * (float)(n * 16 + cc - qw - hi * 4);
  short* Pw = &Ps[w][0];
  const int c0 = tid, c1 = tid + 256;
  const int r0 = c0 >> 3, g0c = c0 & 7;
  const int r1 = c1 >> 3, g1c = c1 & 7;
  const int s0 = r0 * 64 + ((g0c ^ (r0 & 7)) * 8);
  const int s1 = r1 * 64 + ((g1c ^ (r1 & 7)) * 8);
  const short* kbase = qg + (size_t)(b * 2048) * 3072 + 1024 + h * 64;
  const short* vbase = (const short*)vt + (size_t)(b * 16 + h) * 64 * 2048;
  // prologue: stage tile 0
  *(int4v*)(&Ks[0][s0]) = *(const int4v*)(kbase + (size_t)r0 * 3072 + g0c * 8);
  *(int4v*)(&Ks[0][s1]) = *(const int4v*)(kbase + (size_t)r1 * 3072 + g1c * 8);
  *(int4v*)(&Vs[0][s0]) = *(const int4v*)(vbase + (size_t)r0 * 2048 + g0c * 8);
  *(int4v*)(&Vs[0][s1]) = *(const int4v*)(vbase + (size_t)r1 * 2048 + g1c * 8);
  __syncthreads();

  int cur = 0;
  for (int t = 0; t < nt; ++t) {
    int4v kr0, kr1, vr0, vr1;
    const bool havenext = (t + 1 < nt);
    if (havenext) {
      const size_t k0n = (size_t)(t + 1) * 64;
      kr0 = *(const int4v*)(kbase + (k0n + r0) * 3072 + g0c * 8);
      kr1 = *(const int4v*)(kbase + (k0n + r1) * 3072 + g1c * 8);
      vr0 = *(const int4v*)(vbase + (size_t)r0 * 2048 + k0n + g0c * 8);
      vr1 = *(const int4v*)(vbase + (size_t)r1 * 2048 + k0n + g1c * 8);
    }
    const int kv0 = t * 64;
    const short* Ksc = &Ks[cur][0];
    const short* Vsc = &Vs[cur][0];
    f32x4 sacc[4] = {};
    __builtin_amdgcn_s_setprio(1);
#pragma unroll
    for (int kk = 0; kk < 2; ++kk) {
      const int g0r = kk * 4 + hi;
      const bf16x8 aqk = kk ? aq1 : aq0;
#pragma unroll
      for (int n = 0; n < 4; ++n) {
        const int col = n * 16 + cc;
        bf16x8 bk = *(const bf16x8*)(Ksc + col * 64 + ((g0r ^ (col & 7)) * 8));
        sacc[n] = __builtin_amdgcn_mfma_f32_16x16x32_bf16(aqk, bk, sacc[n], 0, 0, 0);
      }
    }
    __builtin_amdgcn_s_setprio(0);
    // ---- no-max softmax + PV ----
    const bool domask = (t == nt - 1);
#pragma unroll
    for (int n = 0; n < 4; ++n) {
#pragma unroll
      for (int j = 0; j < 4; ++j) {
        float v = fmaf(sacc[n][j], C1, base4[n] - slope2 * (float)j);
        if (domask) {
          const int kvg = kv0 + n * 16 + cc;
          const int qrow = qw + hi * 4 + j;
          if (kvg > qrow) v = -1e30f;   // exp2 -> 0
        }
        Pw[(hi * 4 + j) * 80 + n * 16 + cc] = (short)f2b(exp2f(v));
      }
      base4[n] += step;
    }
    __builtin_amdgcn_s_setprio(1);
#pragma unroll
    for (int kk2 = 0; kk2 < 2; ++kk2) {
      bf16x8 pf = *(const bf16x8*)(Pw + cc * 80 + kk2 * 32 + hi * 8);
      rs = __builtin_amdgcn_mfma_f32_16x16x32_bf16(pf, onesf, rs, 0, 0, 0);
#pragma unroll
      for (int n = 0; n < 4; ++n) {
        const int dr = n * 16 + cc;
        bf16x8 vf = *(const bf16x8*)(Vsc + dr * 64 + (((kk2 * 4 + hi) ^ (dr & 7)) * 8));
        oacc[n] = __builtin_amdgcn_mfma_f32_16x16x32_bf16(pf, vf, oacc[n], 0, 0, 0);
      }
    }
    __builtin_amdgcn_s_setprio(0);
    if (havenext) {
      const int nxt = cur ^ 1;
      *(int4v*)(&Ks[nxt][s0]) = kr0;
      *(int4v*)(&Ks[nxt][s1]) = kr1;
      *(int4v*)(&Vs[nxt][s0]) = vr0;
      *(int4v*)(&Vs[nxt][s1]) = vr1;
    }
    __syncthreads();
    cur ^= 1;
  }
  {
    const int rr = hi * 4;
#pragma unroll
    for (int n = 0; n < 4; ++n)
#pragma unroll
      for (int j = 0; j < 4; ++j) {
        const int row = qw + rr + j;
        o[(size_t)(b * 2048 + row) * 1024 + h * 64 + n * 16 + cc] = f2b(oacc[n][j] / rs[j]);
      }
  }
}

extern "C" void kernel_launch(void* const* d_in, const int* in_sizes, int n_in,
                              void* d_out, int out_size, void* d_ws, size_t ws_size,
                              hipStream_t stream) {
  (void)in_sizes; (void)n_in; (void)out_size; (void)ws_size;
  const float* x      = (const float*)d_in[0];
  const float* Wq     = (const float*)d_in[1];
  const float* Wk     = (const float*)d_in[2];
  const float* Wv     = (const float*)d_in[3];
  const float* Wo     = (const float*)d_in[4];
  const float* scale1 = (const float*)d_in[5];
  const float* scale2 = (const float*)d_in[6];
  const float* W1     = (const float*)d_in[7];
  const float* b1     = (const float*)d_in[8];
  const float* Wg     = (const float*)d_in[9];
  const float* bg     = (const float*)d_in[10];
  const float* Wl     = (const float*)d_in[11];
  const float* bl     = (const float*)d_in[12];
  const float* beta   = (const float*)d_in[13];
  float* out = (float*)d_out;

  char* ws = (char*)d_ws;
  float* sums         = (float*)ws;                                    // 256 B
  unsigned short* WT  = (unsigned short*)(ws + 16384);                 // 7M bf16 (14 MB)
  unsigned short* h   = (unsigned short*)(ws + 16384 + 14680064);      // 4M bf16 (8 MB)
  unsigned short* qkv = (unsigned short*)((char*)h + 8388608);         // 12M bf16 (24 MB)
  unsigned short* vt  = (unsigned short*)((char*)qkv + 25165824);      // 4M bf16 (8 MB)
  float* x1           = (float*)((char*)vt + 8388608);                 // 4M fp32 (16 MB)
  unsigned short* ob  = h;                   // reuse (h dead after qkv GEMM)
  unsigned short* t1  = qkv;                 // reuse (qkv dead after attention)

  hipMemsetAsync(sums, 0, 256, stream);

  // --- attention sublayer ---
  k_transpose_w7<<<dim3(32, 32, 7), 256, 0, stream>>>(Wq, Wk, Wv, Wo, W1, Wg, Wl, WT);
  k_reduce_sq<<<dim3(256, 2), 256, 0, stream>>>(x, sums);
  k_rmsnorm<<<4096, 256, 0, stream>>>(x, scale1, sums, h);
  k_gemm<5, 4><<<dim3(24, 32), 256, 0, stream>>>(h, WT, (void*)qkv, nullptr, nullptr, nullptr, nullptr, 3072, nullptr);
  k_transpose_v<<<dim3(2, 64, 32), 256, 0, stream>>>(qkv, vt);
  k_attn<<<1024, 256, 0, stream>>>(qkv, vt, ob);
  k_gemm<1, 2><<<dim3(16, 32), 256, 0, stream>>>(ob, WT + 3145728, (void*)x1, x, nullptr, nullptr, nullptr, 1024, sums + 2);

  // --- FFN sublayer (sums[2..3] filled by fused GEMM epilogue) ---
  k_rmsnorm<<<4096, 256, 0, stream>>>(x1, scale2, sums + 2, h);
  k_gemm<2, 2><<<dim3(16, 32), 256, 0, stream>>>(h, WT + 4194304, (void*)t1, b1, nullptr, nullptr, nullptr, 1024, nullptr);
  k_gemm<4, 4><<<dim3(16, 32), 256, 0, stream>>>(t1, WT + 5242880, (void*)out, bg, bl, x1, beta, 1024, nullptr);
}

// Round 15
// 338.747 us; speedup vs baseline: 1.2566x; 1.0102x over previous
//
#include <hip/hip_runtime.h>
#include <hip/hip_bf16.h>

typedef __attribute__((ext_vector_type(8))) short bf16x8;
typedef __attribute__((ext_vector_type(4))) float f32x4;
typedef __attribute__((ext_vector_type(4))) int int4v;

#define DEV static __device__ __forceinline__

DEV float b2f(unsigned short u) { union { unsigned int i; float f; } c; c.i = ((unsigned int)u) << 16; return c.f; }
DEV unsigned short f2b(float f) {
  __hip_bfloat16 h = __float2bfloat16(f);
  unsigned short u; __builtin_memcpy(&u, &h, 2); return u;
}

DEV void gload16(const void* g, void* l) {
  __builtin_amdgcn_global_load_lds(
      (const __attribute__((address_space(1))) unsigned int*)(g),
      (__attribute__((address_space(3))) unsigned int*)(l), 16, 0, 0);
}

// ---------------- all 7 weight transposes in one launch ----------------
__global__ __launch_bounds__(256) void k_transpose_w7(const float* __restrict__ Wq,
                                                      const float* __restrict__ Wk,
                                                      const float* __restrict__ Wv,
                                                      const float* __restrict__ Wo,
                                                      const float* __restrict__ W1,
                                                      const float* __restrict__ Wg,
                                                      const float* __restrict__ Wl,
                                                      unsigned short* __restrict__ WT) {
  __shared__ float tile[32][33];
  const float* W;
  switch (blockIdx.z) {
    case 0: W = Wq; break; case 1: W = Wk; break; case 2: W = Wv; break;
    case 3: W = Wo; break; case 4: W = W1; break; case 5: W = Wg; break;
    default: W = Wl; break;
  }
  unsigned short* dst = WT + (size_t)blockIdx.z * 1048576;
  const int tx = threadIdx.x & 31, ty = threadIdx.x >> 5;
  const int c0 = blockIdx.x * 32, r0 = blockIdx.y * 32;
#pragma unroll
  for (int i = 0; i < 4; ++i)
    tile[ty + i * 8][tx] = W[(size_t)(r0 + ty + i * 8) * 1024 + c0 + tx];
  __syncthreads();
#pragma unroll
  for (int i = 0; i < 4; ++i)
    dst[(size_t)(c0 + ty + i * 8) * 1024 + r0 + tx] = f2b(tile[tx][ty + i * 8]);
}

// ---------------- per-batch sum of squares ----------------
__global__ __launch_bounds__(256) void k_reduce_sq(const float* __restrict__ x,
                                                   float* __restrict__ sums) {
  const int b = blockIdx.y;
  const float4* xb = (const float4*)(x + (size_t)b * 2097152);
  float s = 0.f;
  for (int i = blockIdx.x * 256 + threadIdx.x; i < 524288; i += 256 * gridDim.x) {
    float4 v = xb[i];
    s += v.x * v.x + v.y * v.y + v.z * v.z + v.w * v.w;
  }
  __shared__ float red[256];
  red[threadIdx.x] = s;
  __syncthreads();
  for (int st = 128; st > 0; st >>= 1) {
    if (threadIdx.x < st) red[threadIdx.x] += red[threadIdx.x + st];
    __syncthreads();
  }
  if (threadIdx.x == 0) atomicAdd(&sums[b], red[0]);
}

// ---------------- rmsnorm ----------------
__global__ __launch_bounds__(256) void k_rmsnorm(const float* __restrict__ x,
                                                 const float* __restrict__ scale,
                                                 const float* __restrict__ sums,
                                                 unsigned short* __restrict__ out) {
  const int idx = blockIdx.x * 256 + threadIdx.x;
  const int e = idx * 4;
  const int m = e >> 10, d = e & 1023;
  const int b = m >> 11, s = m & 2047;
  const float inv = rsqrtf(sums[b] * (1.0f / 2097152.0f));
  float4 xv = *(const float4*)(x + (size_t)e);
  float4 sv = *(const float4*)(scale + (size_t)s * 1024 + d);
  ushort4 o;
  o.x = f2b(xv.x * sv.x * inv); o.y = f2b(xv.y * sv.y * inv);
  o.z = f2b(xv.z * sv.z * inv); o.w = f2b(xv.w * sv.w * inv);
  *(ushort4*)(out + e) = o;
}

// ---------------- GEMM: C[4096,N] = A[4096,1024] @ Bt[N,1024]^T ----------------
// 2-phase pipeline: double-buffered LDS, next-tile global_load_lds issued
// BEFORE current-tile compute, one barrier per iter.
// EPI 1: fp32 (aux[row,col]+acc) + fused batch sumsq. EPI 2: bf16 (acc+aux[col]).
// EPI 4: fused SwiGLU. EPI 5: bf16 store with fused RoPE for cols<2048.
template <int EPI, int NREP>
__global__ __launch_bounds__(256) void k_gemm(const unsigned short* __restrict__ A,
                                              const unsigned short* __restrict__ Bt,
                                              void* __restrict__ Cout,
                                              const float* __restrict__ aux,
                                              const float* __restrict__ aux2,
                                              const float* __restrict__ x1p,
                                              const float* __restrict__ betap,
                                              const int N,
                                              float* __restrict__ ss) {
  constexpr int BN = NREP * 32;
  __shared__ short As[2][128 * 64];
  __shared__ short Bs[2][BN * 64];
  const int tid = threadIdx.x;
  const int w = tid >> 6, l = tid & 63;
  const int brow = blockIdx.y * 128;
  const int bcol = blockIdx.x * (EPI == 4 ? 64 : BN);
  const int wr = (w >> 1) * 64;
  const int wc = (EPI == 4) ? (w & 1) * 32 : (w & 1) * (NREP * 16);
  const int lr = l >> 3, lg = l & 7;
  f32x4 acc[4][NREP] = {};
  const short* Ag = (const short*)A;
  const short* Bg = (const short*)Bt;

  auto STAGE = [&](int buf, int k0) {
#pragma unroll
    for (int p = 0; p < 4; ++p) {
      const int row = p * 32 + w * 8 + lr;
      gload16(Ag + (size_t)(brow + row) * 1024 + k0 + lg * 8,
              (char*)&As[buf][0] + (size_t)(p * 32 + w * 8) * 128);
    }
#pragma unroll
    for (int p = 0; p < NREP; ++p) {
      const int row = p * 32 + w * 8 + lr;
      size_t goff;
      if (EPI == 4 && p >= 2)
        goff = (size_t)1048576 + (size_t)(bcol + row - 64) * 1024;  // Wl section
      else
        goff = (size_t)(bcol + row) * 1024;
      gload16(Bg + goff + k0 + lg * 8,
              (char*)&Bs[buf][0] + (size_t)(p * 32 + w * 8) * 128);
    }
  };

  STAGE(0, 0);
  __syncthreads();  // drains vmcnt -> tile 0 visible
  int cur = 0;
  for (int t = 0; t < 16; ++t) {
    if (t < 15) STAGE(cur ^ 1, (t + 1) * 64);  // prefetch next tile (other buffer)
#pragma unroll
    for (int kk = 0; kk < 2; ++kk) {
      const int g0 = kk * 4 + (l >> 4);
      bf16x8 af[4], bfr[NREP];
#pragma unroll
      for (int m = 0; m < 4; ++m)
        af[m] = *(const bf16x8*)(&As[cur][0] + (wr + m * 16 + (l & 15)) * 64 + g0 * 8);
#pragma unroll
      for (int n = 0; n < NREP; ++n) {
        int bsrow;
        if (EPI == 4) bsrow = (n < 2) ? (wc + n * 16 + (l & 15)) : (64 + wc + (n - 2) * 16 + (l & 15));
        else bsrow = wc + n * 16 + (l & 15);
        bfr[n] = *(const bf16x8*)(&Bs[cur][0] + bsrow * 64 + g0 * 8);
      }
      __builtin_amdgcn_s_setprio(1);
#pragma unroll
      for (int m = 0; m < 4; ++m)
#pragma unroll
        for (int n = 0; n < NREP; ++n)
          acc[m][n] = __builtin_amdgcn_mfma_f32_16x16x32_bf16(af[m], bfr[n], acc[m][n], 0, 0, 0);
      __builtin_amdgcn_s_setprio(0);
    }
    __syncthreads();  // drains prefetch vmcnt + protects cur from next overwrite
    cur ^= 1;
  }
  const int rr = (l >> 4) * 4, cc = l & 15;
  if (EPI == 5) {
    const bool dorope = (bcol < 2048);   // block-uniform (128-col tiles align to 2048)
    if (dorope) {
      float th[NREP];
#pragma unroll
      for (int n = 0; n < NREP; ++n)
        th[n] = exp2f(-((float)(((bcol + wc + n * 16 + cc) & 1023) >> 1) - 1.0f) * 0.0259525627f);
#pragma unroll
      for (int m = 0; m < 4; ++m)
#pragma unroll
        for (int n = 0; n < NREP; ++n) {
          const int col = bcol + wc + n * 16 + cc;
#pragma unroll
          for (int j = 0; j < 4; ++j) {
            const int row = brow + wr + m * 16 + rr + j;
            const float vo = acc[m][n][j];
            const float vp = __shfl_xor(vo, 1);  // partner column (col^1)
            float sn, cs;
            __sincosf((float)(row & 2047) * th[n], &sn, &cs);
            const float r = (cc & 1) ? (cs * vo - sn * vp) : (cs * vo + sn * vp);
            ((unsigned short*)Cout)[(size_t)row * N + col] = f2b(r);
          }
        }
    } else {
#pragma unroll
      for (int m = 0; m < 4; ++m)
#pragma unroll
        for (int n = 0; n < NREP; ++n) {
          const int col = bcol + wc + n * 16 + cc;
#pragma unroll
          for (int j = 0; j < 4; ++j) {
            const int row = brow + wr + m * 16 + rr + j;
            ((unsigned short*)Cout)[(size_t)row * N + col] = f2b(acc[m][n][j]);
          }
        }
    }
    return;
  }
  if (EPI == 4) {
    const float bt = betap[0];
#pragma unroll
    for (int m = 0; m < 4; ++m)
#pragma unroll
      for (int nn = 0; nn < 2; ++nn) {
        const int col = bcol + wc + nn * 16 + cc;
#pragma unroll
        for (int j = 0; j < 4; ++j) {
          const int row = brow + wr + m * 16 + rr + j;
          const float gv = acc[m][nn][j] + aux[col];
          const float lv = acc[m][nn + 2][j] + aux2[col];
          const float sw = gv / (1.f + __expf(-bt * gv));
          ((float*)Cout)[(size_t)row * 1024 + col] = x1p[(size_t)row * 1024 + col] + sw * lv;
        }
      }
    return;
  }
  float sq = 0.f;
#pragma unroll
  for (int m = 0; m < 4; ++m)
#pragma unroll
    for (int n = 0; n < NREP; ++n) {
      const int col = bcol + wc + n * 16 + cc;
#pragma unroll
      for (int j = 0; j < 4; ++j) {
        const int row = brow + wr + m * 16 + rr + j;
        float v = acc[m][n][j];
        if (EPI == 1) {
          const float v2 = aux[(size_t)row * N + col] + v;
          ((float*)Cout)[(size_t)row * N + col] = v2;
          sq += v2 * v2;
        } else {
          ((unsigned short*)Cout)[(size_t)row * N + col] = f2b(v + aux[col]);
        }
      }
    }
  if (EPI == 1) {
#pragma unroll
    for (int off = 1; off < 64; off <<= 1) sq += __shfl_xor(sq, off);
    if (l == 0) atomicAdd(&ss[brow >> 11], sq);
  }
}

// ---------------- V transpose + fused RoPE on V ----------------
__global__ __launch_bounds__(256) void k_transpose_v(const unsigned short* __restrict__ qkv,
                                                     unsigned short* __restrict__ vt) {
  __shared__ unsigned short tile[32][33];
  const int tx = threadIdx.x & 31, ty = threadIdx.x >> 5;
  const int bh = blockIdx.z;
  const int b = bh >> 4, h = bh & 15;
  const int d0 = blockIdx.x * 32, s0 = blockIdx.y * 32;
#pragma unroll
  for (int i = 0; i < 4; ++i)
    tile[ty + i * 8][tx] = qkv[(size_t)(b * 2048 + s0 + ty + i * 8) * 3072 + 2048 + h * 64 + d0 + tx];
  __syncthreads();
  const float sv = (float)(s0 + tx);
  const int par = ty & 1;
#pragma unroll
  for (int i = 0; i < 4; ++i) {
    const int dsec = h * 64 + d0 + ty + i * 8;   // d within the 1024-wide V section
    const float th = exp2f(-((float)(dsec >> 1) - 1.0f) * 0.0259525627f);
    float sn, cs;
    __sincosf(sv * th, &sn, &cs);
    const float vo = b2f(tile[tx][ty + i * 8]);
    const float vp = b2f(tile[tx][(ty ^ 1) + i * 8]);  // partner d^1, same s
    const float r = par ? (cs * vo - sn * vp) : (cs * vo + sn * vp);
    vt[((size_t)bh * 64 + d0 + ty + i * 8) * 2048 + s0 + tx] = f2b(r);
  }
}

// ---------------- flash attention v7: single-chain, grid 1024, XCD-grouped + length-mixed ----------------
// One q-tile per block, 4 waves. Map: all 32 q-tiles of one (b,h) land at ids with the
// SAME id%8 (same XCD via round-robin dispatch) -> K/V stays L2-resident (2MB/XCD);
// qt rotated within each class so dispatch order mixes tile lengths (CU balance).
// No-max softmax (round-12 validated).
__global__ __launch_bounds__(256) void k_attn(const unsigned short* __restrict__ qkv,
                                              const unsigned short* __restrict__ vt,
                                              unsigned short* __restrict__ o) {
  __shared__ short Ks[2][4096];
  __shared__ short Vs[2][4096];
  __shared__ short Ps[4][1280];
  const int id = blockIdx.x;
  const int cls = id & 7;               // XCD class
  const int k = id >> 3;                // 0..127
  const int gidx = cls + 8 * (k & 3);   // (b,h) group, constant id%8 per group
  const int qt = ((k >> 2) + 8 * (k & 3)) & 31;  // bijective per group; mixes lengths
  const int h = gidx & 15, b = gidx >> 4;
  const int nt = qt + 1;
  const int tid = threadIdx.x, w = tid >> 6, l = tid & 63;
  const int cc = l & 15, hi = l >> 4;
  const int qw = qt * 64 + w * 16;
  const short* qg = (const short*)qkv;
  bf16x8 aq0, aq1;
  {
    const short* base = qg + (size_t)(b * 2048 + qw + cc) * 3072 + h * 64 + hi * 8;
    aq0 = *(const bf16x8*)base;
    aq1 = *(const bf16x8*)(base + 32);
  }
  const float slope2 = exp2f(-0.5f * (float)(h + 1)) * 1.44269504f;  // log2 domain
  const float C1 = 0.125f * 1.44269504f;
  const float step = slope2 * 64.f;
  bf16x8 onesf;
#pragma unroll
  for (int z = 0; z < 8; ++z) onesf[z] = (short)0x3F80;  // bf16 1.0
  f32x4 oacc[4] = {};
  f32x4 rs = {};
  float base4[4];
#pragma unroll
  for (int n = 0; n < 4; ++n)
    base4[n] = slope2 * (float)(n * 16 + cc - qw - hi * 4);
  short* Pw = &Ps[w][0];
  const int c0 = tid, c1 = tid + 256;
  const int r0 = c0 >> 3, g0c = c0 & 7;
  const int r1 = c1 >> 3, g1c = c1 & 7;
  const int s0 = r0 * 64 + ((g0c ^ (r0 & 7)) * 8);
  const int s1 = r1 * 64 + ((g1c ^ (r1 & 7)) * 8);
  const short* kbase = qg + (size_t)(b * 2048) * 3072 + 1024 + h * 64;
  const short* vbase = (const short*)vt + (size_t)(b * 16 + h) * 64 * 2048;
  // prologue: stage tile 0
  *(int4v*)(&Ks[0][s0]) = *(const int4v*)(kbase + (size_t)r0 * 3072 + g0c * 8);
  *(int4v*)(&Ks[0][s1]) = *(const int4v*)(kbase + (size_t)r1 * 3072 + g1c * 8);
  *(int4v*)(&Vs[0][s0]) = *(const int4v*)(vbase + (size_t)r0 * 2048 + g0c * 8);
  *(int4v*)(&Vs[0][s1]) = *(const int4v*)(vbase + (size_t)r1 * 2048 + g1c * 8);
  __syncthreads();

  int cur = 0;
  for (int t = 0; t < nt; ++t) {
    int4v kr0, kr1, vr0, vr1;
    const bool havenext = (t + 1 < nt);
    if (havenext) {
      const size_t k0n = (size_t)(t + 1) * 64;
      kr0 = *(const int4v*)(kbase + (k0n + r0) * 3072 + g0c * 8);
      kr1 = *(const int4v*)(kbase + (k0n + r1) * 3072 + g1c * 8);
      vr0 = *(const int4v*)(vbase + (size_t)r0 * 2048 + k0n + g0c * 8);
      vr1 = *(const int4v*)(vbase + (size_t)r1 * 2048 + k0n + g1c * 8);
    }
    const int kv0 = t * 64;
    const short* Ksc = &Ks[cur][0];
    const short* Vsc = &Vs[cur][0];
    f32x4 sacc[4] = {};
    __builtin_amdgcn_s_setprio(1);
#pragma unroll
    for (int kk = 0; kk < 2; ++kk) {
      const int g0r = kk * 4 + hi;
      const bf16x8 aqk = kk ? aq1 : aq0;
#pragma unroll
      for (int n = 0; n < 4; ++n) {
        const int col = n * 16 + cc;
        bf16x8 bk = *(const bf16x8*)(Ksc + col * 64 + ((g0r ^ (col & 7)) * 8));
        sacc[n] = __builtin_amdgcn_mfma_f32_16x16x32_bf16(aqk, bk, sacc[n], 0, 0, 0);
      }
    }
    __builtin_amdgcn_s_setprio(0);
    // ---- no-max softmax + PV ----
    const bool domask = (t == nt - 1);
#pragma unroll
    for (int n = 0; n < 4; ++n) {
#pragma unroll
      for (int j = 0; j < 4; ++j) {
        float v = fmaf(sacc[n][j], C1, base4[n] - slope2 * (float)j);
        if (domask) {
          const int kvg = kv0 + n * 16 + cc;
          const int qrow = qw + hi * 4 + j;
          if (kvg > qrow) v = -1e30f;   // exp2 -> 0
        }
        Pw[(hi * 4 + j) * 80 + n * 16 + cc] = (short)f2b(exp2f(v));
      }
      base4[n] += step;
    }
    __builtin_amdgcn_s_setprio(1);
#pragma unroll
    for (int kk2 = 0; kk2 < 2; ++kk2) {
      bf16x8 pf = *(const bf16x8*)(Pw + cc * 80 + kk2 * 32 + hi * 8);
      rs = __builtin_amdgcn_mfma_f32_16x16x32_bf16(pf, onesf, rs, 0, 0, 0);
#pragma unroll
      for (int n = 0; n < 4; ++n) {
        const int dr = n * 16 + cc;
        bf16x8 vf = *(const bf16x8*)(Vsc + dr * 64 + (((kk2 * 4 + hi) ^ (dr & 7)) * 8));
        oacc[n] = __builtin_amdgcn_mfma_f32_16x16x32_bf16(pf, vf, oacc[n], 0, 0, 0);
      }
    }
    __builtin_amdgcn_s_setprio(0);
    if (havenext) {
      const int nxt = cur ^ 1;
      *(int4v*)(&Ks[nxt][s0]) = kr0;
      *(int4v*)(&Ks[nxt][s1]) = kr1;
      *(int4v*)(&Vs[nxt][s0]) = vr0;
      *(int4v*)(&Vs[nxt][s1]) = vr1;
    }
    __syncthreads();
    cur ^= 1;
  }
  {
    const int rr = hi * 4;
#pragma unroll
    for (int n = 0; n < 4; ++n)
#pragma unroll
      for (int j = 0; j < 4; ++j) {
        const int row = qw + rr + j;
        o[(size_t)(b * 2048 + row) * 1024 + h * 64 + n * 16 + cc] = f2b(oacc[n][j] / rs[j]);
      }
  }
}

extern "C" void kernel_launch(void* const* d_in, const int* in_sizes, int n_in,
                              void* d_out, int out_size, void* d_ws, size_t ws_size,
                              hipStream_t stream) {
  (void)in_sizes; (void)n_in; (void)out_size; (void)ws_size;
  const float* x      = (const float*)d_in[0];
  const float* Wq     = (const float*)d_in[1];
  const float* Wk     = (const float*)d_in[2];
  const float* Wv     = (const float*)d_in[3];
  const float* Wo     = (const float*)d_in[4];
  const float* scale1 = (const float*)d_in[5];
  const float* scale2 = (const float*)d_in[6];
  const float* W1     = (const float*)d_in[7];
  const float* b1     = (const float*)d_in[8];
  const float* Wg     = (const float*)d_in[9];
  const float* bg     = (const float*)d_in[10];
  const float* Wl     = (const float*)d_in[11];
  const float* bl     = (const float*)d_in[12];
  const float* beta   = (const float*)d_in[13];
  float* out = (float*)d_out;

  char* ws = (char*)d_ws;
  float* sums         = (float*)ws;                                    // 256 B
  unsigned short* WT  = (unsigned short*)(ws + 16384);                 // 7M bf16 (14 MB)
  unsigned short* h   = (unsigned short*)(ws + 16384 + 14680064);      // 4M bf16 (8 MB)
  unsigned short* qkv = (unsigned short*)((char*)h + 8388608);         // 12M bf16 (24 MB)
  unsigned short* vt  = (unsigned short*)((char*)qkv + 25165824);      // 4M bf16 (8 MB)
  float* x1           = (float*)((char*)vt + 8388608);                 // 4M fp32 (16 MB)
  unsigned short* ob  = h;                   // reuse (h dead after qkv GEMM)
  unsigned short* t1  = qkv;                 // reuse (qkv dead after attention)

  hipMemsetAsync(sums, 0, 256, stream);

  // --- attention sublayer ---
  k_transpose_w7<<<dim3(32, 32, 7), 256, 0, stream>>>(Wq, Wk, Wv, Wo, W1, Wg, Wl, WT);
  k_reduce_sq<<<dim3(256, 2), 256, 0, stream>>>(x, sums);
  k_rmsnorm<<<4096, 256, 0, stream>>>(x, scale1, sums, h);
  k_gemm<5, 4><<<dim3(24, 32), 256, 0, stream>>>(h, WT, (void*)qkv, nullptr, nullptr, nullptr, nullptr, 3072, nullptr);
  k_transpose_v<<<dim3(2, 64, 32), 256, 0, stream>>>(qkv, vt);
  k_attn<<<1024, 256, 0, stream>>>(qkv, vt, ob);
  k_gemm<1, 2><<<dim3(16, 32), 256, 0, stream>>>(ob, WT + 3145728, (void*)x1, x, nullptr, nullptr, nullptr, 1024, sums + 2);

  // --- FFN sublayer (sums[2..3] filled by fused GEMM epilogue) ---
  k_rmsnorm<<<4096, 256, 0, stream>>>(x1, scale2, sums + 2, h);
  k_gemm<2, 2><<<dim3(16, 32), 256, 0, stream>>>(h, WT + 4194304, (void*)t1, b1, nullptr, nullptr, nullptr, 1024, nullptr);
  k_gemm<4, 4><<<dim3(16, 32), 256, 0, stream>>>(t1, WT + 5242880, (void*)out, bg, bl, x1, beta, 1024, nullptr);
}